// Round 3
// baseline (3292.506 us; speedup 1.0000x reference)
//
#include <hip/hip_runtime.h>
#include <math.h>

// Problem constants
#define B_    4096
#define D_    2048
#define K_    16384
#define SIDE  128

// GEMM tiling
#define BM 128
#define BN 128
#define BD 16
#define ASTR 132   // BM + 4 pad: keeps 16B alignment, breaks write conflicts to 2-way

// Argmin refinement
#define EPS_CAND 4e-3f
#define MAXCAND  32

// ---------------- k2 = column sums of kernel^2 ----------------
__global__ void k2_partial(const float* __restrict__ kmat, float* __restrict__ pk2) {
    int k  = blockIdx.x * 256 + threadIdx.x;
    int d0 = blockIdx.y * 256;
    float s = 0.f;
    #pragma unroll 8
    for (int d = 0; d < 256; ++d) {
        float v = kmat[(size_t)(d0 + d) * K_ + k];
        s = fmaf(v, v, s);
    }
    pk2[(size_t)blockIdx.y * K_ + k] = s;
}

__global__ void k2_reduce(const float* __restrict__ pk2, float* __restrict__ k2) {
    int k = blockIdx.x * 256 + threadIdx.x;
    float s = 0.f;
    #pragma unroll
    for (int j = 0; j < 8; ++j) s += pk2[(size_t)j * K_ + k];
    k2[k] = s;
}

// ---------------- x2 = row sums of x^2 ----------------
__global__ void x2_kernel(const float* __restrict__ x, float* __restrict__ x2) {
    int row = blockIdx.x;
    const float* xr = x + (size_t)row * D_;
    int t = threadIdx.x; // 256 threads, 8 elems each
    float4 v0 = ((const float4*)xr)[t];
    float4 v1 = ((const float4*)xr)[t + 256];
    float s = v0.x*v0.x + v0.y*v0.y + v0.z*v0.z + v0.w*v0.w
            + v1.x*v1.x + v1.y*v1.y + v1.z*v1.z + v1.w*v1.w;
    __shared__ float red[256];
    red[t] = s; __syncthreads();
    for (int off = 128; off > 0; off >>= 1) {
        if (t < off) red[t] += red[t + off];
        __syncthreads();
    }
    if (t == 0) x2[row] = red[0];
}

// ---------------- fused GEMM -> norms2 -> d_out ----------------
__global__ __launch_bounds__(256) void gemm_norms(
    const float* __restrict__ X, const float* __restrict__ Kmat,
    const float* __restrict__ x2, const float* __restrict__ k2,
    float* __restrict__ out)
{
    __shared__ float As[BD * ASTR];   // As[dd][m], transposed x tile
    __shared__ float Bs[BD * BN];     // Bs[dd][kk]

    const int tid = threadIdx.x;
    const int tx = tid & 15, ty = tid >> 4;
    const int bn0 = blockIdx.x * BN;
    const int bm0 = blockIdx.y * BM;

    float acc[8][8];
    #pragma unroll
    for (int i = 0; i < 8; ++i)
        #pragma unroll
        for (int j = 0; j < 8; ++j) acc[i][j] = 0.f;

    // load-thread mapping
    const int lm = tid >> 2;          // 0..63  (row within tile, +64 second pass)
    const int ld = (tid & 3) << 2;    // 0,4,8,12 (d within tile)
    const int bd = tid >> 5;          // 0..7   (d row, +8 second pass)
    const int bk = (tid & 31) << 2;   // 0..124 (col within tile)

    const float* Xp = X    + (size_t)(bm0 + lm) * D_ + ld;
    const float* Kp = Kmat + (size_t)bd * K_ + bn0 + bk;

    // prefetch first tile
    float4 a0 = *(const float4*)(Xp);
    float4 a1 = *(const float4*)(Xp + (size_t)64 * D_);
    float4 b0 = *(const float4*)(Kp);
    float4 b1 = *(const float4*)(Kp + (size_t)8 * K_);

    const int NT = D_ / BD;
    for (int kt = 0; kt < NT; ++kt) {
        __syncthreads();   // previous compute done before overwrite
        As[(ld+0)*ASTR + lm]      = a0.x;
        As[(ld+1)*ASTR + lm]      = a0.y;
        As[(ld+2)*ASTR + lm]      = a0.z;
        As[(ld+3)*ASTR + lm]      = a0.w;
        As[(ld+0)*ASTR + lm + 64] = a1.x;
        As[(ld+1)*ASTR + lm + 64] = a1.y;
        As[(ld+2)*ASTR + lm + 64] = a1.z;
        As[(ld+3)*ASTR + lm + 64] = a1.w;
        *(float4*)&Bs[bd*BN + bk]     = b0;
        *(float4*)&Bs[(bd+8)*BN + bk] = b1;
        __syncthreads();

        if (kt + 1 < NT) {   // prefetch next tile (overlaps compute)
            const float* Xn = Xp + (kt + 1) * BD;
            const float* Kn = Kp + (size_t)(kt + 1) * BD * K_;
            a0 = *(const float4*)(Xn);
            a1 = *(const float4*)(Xn + (size_t)64 * D_);
            b0 = *(const float4*)(Kn);
            b1 = *(const float4*)(Kn + (size_t)8 * K_);
        }

        #pragma unroll
        for (int dd = 0; dd < BD; ++dd) {
            float4 A0 = *(const float4*)&As[dd*ASTR + ty*4];
            float4 A1 = *(const float4*)&As[dd*ASTR + ty*4 + 64];
            float4 B0 = *(const float4*)&Bs[dd*BN + tx*4];
            float4 B1 = *(const float4*)&Bs[dd*BN + tx*4 + 64];
            float a[8] = {A0.x,A0.y,A0.z,A0.w,A1.x,A1.y,A1.z,A1.w};
            float b[8] = {B0.x,B0.y,B0.z,B0.w,B1.x,B1.y,B1.z,B1.w};
            #pragma unroll
            for (int i = 0; i < 8; ++i)
                #pragma unroll
                for (int j = 0; j < 8; ++j)
                    acc[i][j] = fmaf(a[i], b[j], acc[i][j]);
        }
    }

    // ---- epilogue: norms2 = max(x2 - 2*dot + k2, 0), store ----
    int rl[8], cl[8];
    #pragma unroll
    for (int i = 0; i < 4; ++i) {
        rl[i] = ty*4 + i;  rl[i+4] = ty*4 + 64 + i;
        cl[i] = tx*4 + i;  cl[i+4] = tx*4 + 64 + i;
    }
    float xr[8], kc[8];
    #pragma unroll
    for (int i = 0; i < 8; ++i) { xr[i] = x2[bm0 + rl[i]]; kc[i] = k2[bn0 + cl[i]]; }

    #pragma unroll
    for (int i = 0; i < 8; ++i) {
        float vv[8];
        #pragma unroll
        for (int j = 0; j < 8; ++j)
            vv[j] = fmaxf((xr[i] - 2.f * acc[i][j]) + kc[j], 0.f);

        int gr = bm0 + rl[i];
        *(float4*)&out[(size_t)gr * K_ + bn0 + tx*4]      = make_float4(vv[0],vv[1],vv[2],vv[3]);
        *(float4*)&out[(size_t)gr * K_ + bn0 + tx*4 + 64] = make_float4(vv[4],vv[5],vv[6],vv[7]);
    }
}

// ---------------- per-row argmin, emulating numpy's per-op f32-rounded pipeline ----------------
// Gold model: each primitive computed exactly then rounded to f32:
//   x2f = f32(sum_f64(f32(x*x))), dotf = f32(sum_f64(x*w)), k2f = f32(sum_f64(f32(w*w)))
//   score = f32(f32(x2f - f32(2*dotf)) + k2f), clamped at 0; argmin ties -> first index.
__global__ __launch_bounds__(256) void rowscan(
    const float* __restrict__ out, const float* __restrict__ X,
    const float* __restrict__ Kmat, int* __restrict__ widx)
{
    const int row = blockIdx.x;
    const int t = threadIdx.x;
    const float* orow = out + (size_t)row * K_;

    // pass 1: row min of our stored f32 norms2
    float mn = 3.4e38f;
    for (int i = t; i < K_/4; i += 256) {
        float4 v = ((const float4*)orow)[i];
        mn = fminf(mn, fminf(fminf(v.x, v.y), fminf(v.z, v.w)));
    }
    __shared__ float smin[256];
    smin[t] = mn; __syncthreads();
    for (int off = 128; off > 0; off >>= 1) {
        if (t < off) smin[t] = fminf(smin[t], smin[t+off]);
        __syncthreads();
    }
    const float rowmin = smin[0];

    // pass 2: collect all candidates within EPS of min (expected: 1, sometimes 2-3)
    __shared__ int scnt;
    __shared__ int cand[MAXCAND];
    if (t == 0) scnt = 0;
    __syncthreads();
    const float thr = rowmin + EPS_CAND;
    for (int i = t; i < K_/4; i += 256) {
        float4 v = ((const float4*)orow)[i];
        float vv[4] = {v.x, v.y, v.z, v.w};
        #pragma unroll
        for (int j = 0; j < 4; ++j) {
            if (vv[j] <= thr) {
                int p = atomicAdd(&scnt, 1);
                if (p < MAXCAND) cand[p] = i*4 + j;
            }
        }
    }
    __syncthreads();
    const int cnt = min(scnt, MAXCAND);
    if (cnt == 1) {
        if (t == 0) widx[row] = cand[0];
        return;
    }

    // ---- refine with the emulated-gold f32 scores ----
    const float* xrow = X + (size_t)row * D_;
    __shared__ double sred[256];

    // x2f: squares rounded to f32 (the x*x primitive), exact f64 sum, one rounding
    double xs = 0.0;
    for (int d = t; d < D_; d += 256) {
        float xv = xrow[d];
        float sq = xv * xv;          // f32-rounded square
        xs += (double)sq;
    }
    sred[t] = xs; __syncthreads();
    for (int off = 128; off > 0; off >>= 1) {
        if (t < off) sred[t] += sred[t+off];
        __syncthreads();
    }
    const float x2f = (float)sred[0];
    __syncthreads();

    __shared__ float cscore[MAXCAND];
    for (int c = 0; c < cnt; ++c) {
        const int k = cand[c];
        double dt = 0.0, kk = 0.0;
        for (int d = t; d < D_; d += 256) {
            float w  = Kmat[(size_t)d * K_ + k];
            float xv = xrow[d];
            dt += (double)xv * (double)w;   // exact product, f64 accumulate
            float w2 = w * w;               // f32-rounded square
            kk += (double)w2;
        }
        sred[t] = dt; __syncthreads();
        for (int off = 128; off > 0; off >>= 1) {
            if (t < off) sred[t] += sred[t+off];
            __syncthreads();
        }
        const float dotf = (float)sred[0];
        __syncthreads();
        sred[t] = kk; __syncthreads();
        for (int off = 128; off > 0; off >>= 1) {
            if (t < off) sred[t] += sred[t+off];
            __syncthreads();
        }
        if (t == 0) {
            const float k2f = (float)sred[0];
            // same op order & f32 rounding as the reference expression
            cscore[c] = fmaxf((x2f - 2.0f * dotf) + k2f, 0.0f);
        }
        __syncthreads();
    }
    if (t == 0) {
        float bv = cscore[0]; int bi = cand[0];
        for (int c = 1; c < cnt; ++c) {
            if (cscore[c] < bv || (cscore[c] == bv && cand[c] < bi)) {
                bv = cscore[c]; bi = cand[c];
            }
        }
        widx[row] = bi;
    }
}

// ---------------- finalize: out *= radials (in place) ----------------
__global__ void finalize(float* __restrict__ out, const int* __restrict__ widx,
                         const float* __restrict__ sigma) {
    size_t gid = (size_t)blockIdx.x * blockDim.x + threadIdx.x; // one float4 each
    int row = (int)(gid / (K_ / 4));
    int c4  = (int)(gid % (K_ / 4)) * 4;
    int w = widx[row];
    float wx = (float)(w >> 7), wy = (float)(w & 127);
    float sg = sigma[0];
    float ninv  = -0.5f / (sg * sg);
    float scale = 1.0f / (sg * sqrtf(2.0f * 3.14159265358979323846f));
    float4 v = *(float4*)&out[(size_t)row * K_ + c4];
    float* vp = (float*)&v;
    #pragma unroll
    for (int j = 0; j < 4; ++j) {
        int k = c4 + j;
        float gx = (float)(k >> 7), gy = (float)(k & 127);
        float dx = gx - wx, dy = gy - wy;
        float d2 = dx*dx + dy*dy;
        vp[j] = vp[j] * (__expf(ninv * d2) * scale);
    }
    *(float4*)&out[(size_t)row * K_ + c4] = v;
}

extern "C" void kernel_launch(void* const* d_in, const int* in_sizes, int n_in,
                              void* d_out, int out_size, void* d_ws, size_t ws_size,
                              hipStream_t stream) {
    const float* x     = (const float*)d_in[0];
    const float* kmat  = (const float*)d_in[1];
    const float* sigma = (const float*)d_in[2];
    float* out = (float*)d_out;
    float* ws  = (float*)d_ws;

    // ws layout (floats): k2[16384] | x2[4096] | widx[4096] | pk2[8*16384]
    float* k2   = ws;
    float* x2   = ws + 16384;
    int*   widx = (int*)(ws + 20480);
    float* pk2  = ws + 24576;
    // total ~622 KB of ws

    k2_partial<<<dim3(K_/256, 8), 256, 0, stream>>>(kmat, pk2);
    k2_reduce <<<K_/256, 256, 0, stream>>>(pk2, k2);
    x2_kernel <<<B_, 256, 0, stream>>>(x, x2);
    gemm_norms<<<dim3(K_/BN, B_/BM), 256, 0, stream>>>(x, kmat, x2, k2, out);
    rowscan   <<<B_, 256, 0, stream>>>(out, x, kmat, widx);
    finalize  <<<(size_t)B_ * (K_/4) / 256, 256, 0, stream>>>(out, widx, sigma);
}

// Round 4
// 743.224 us; speedup vs baseline: 4.4300x; 4.4300x over previous
//
#include <hip/hip_runtime.h>
#include <math.h>

// Problem constants
#define B_    4096
#define D_    2048
#define K_    16384
#define SIDE  128

// f32-fallback GEMM tiling
#define BM 128
#define BN 128
#define BD 16
#define ASTR 132

// Argmin refinement
#define EPS_CAND 0.04f
#define MAXCAND  64

typedef __attribute__((ext_vector_type(8))) short bf16x8;
typedef __attribute__((ext_vector_type(4))) float f32x4;

__device__ __forceinline__ short bf16_rne(float f) {
    unsigned u = __float_as_uint(f);
    unsigned r = u + 0x7FFFu + ((u >> 16) & 1u);
    return (short)(r >> 16);
}

__device__ __forceinline__ void gload16(const void* g, void* l) {
    __builtin_amdgcn_global_load_lds(
        (const __attribute__((address_space(1))) unsigned int*)g,
        (__attribute__((address_space(3))) unsigned int*)l, 16, 0, 0);
}

// ---------------- pack x -> Ah (bf16, same layout) ----------------
__global__ __launch_bounds__(256) void pack_a(const float* __restrict__ x, short* __restrict__ Ah) {
    size_t i = ((size_t)blockIdx.x * 256 + threadIdx.x) * 8;
    float4 v0 = *(const float4*)&x[i];
    float4 v1 = *(const float4*)&x[i + 4];
    short tmp[8] = { bf16_rne(v0.x), bf16_rne(v0.y), bf16_rne(v0.z), bf16_rne(v0.w),
                     bf16_rne(v1.x), bf16_rne(v1.y), bf16_rne(v1.z), bf16_rne(v1.w) };
    *(int4*)&Ah[i] = *(const int4*)tmp;
}

// ---------------- pack kernel -> Bt (bf16, transposed [n][d]) ----------------
__global__ __launch_bounds__(256) void pack_bt(const float* __restrict__ kmat, short* __restrict__ Bt) {
    __shared__ float tile[64][65];
    const int n0 = blockIdx.x * 64, d0 = blockIdx.y * 64;
    const int t = threadIdx.x;
    const int lr = t >> 4, lc4 = (t & 15) * 4;
    #pragma unroll
    for (int r = 0; r < 4; ++r) {
        float4 v = *(const float4*)&kmat[(size_t)(d0 + lr + r*16) * K_ + n0 + lc4];
        tile[lr + r*16][lc4 + 0] = v.x;
        tile[lr + r*16][lc4 + 1] = v.y;
        tile[lr + r*16][lc4 + 2] = v.z;
        tile[lr + r*16][lc4 + 3] = v.w;
    }
    __syncthreads();
    const int n = t >> 2, dc = (t & 3) * 16;
    short tmp[16];
    #pragma unroll
    for (int i = 0; i < 16; ++i) tmp[i] = bf16_rne(tile[dc + i][n]);
    short* dst = &Bt[(size_t)(n0 + n) * 2048 + d0 + dc];
    *(int4*)dst       = *(const int4*)tmp;
    *(int4*)(dst + 8) = *(const int4*)(tmp + 8);
}

// ---------------- k2 = column sums of kernel^2 ----------------
__global__ void k2_partial(const float* __restrict__ kmat, float* __restrict__ pk2) {
    int k  = blockIdx.x * 256 + threadIdx.x;
    int d0 = blockIdx.y * 256;
    float s = 0.f;
    #pragma unroll 8
    for (int d = 0; d < 256; ++d) {
        float v = kmat[(size_t)(d0 + d) * K_ + k];
        s = fmaf(v, v, s);
    }
    pk2[(size_t)blockIdx.y * K_ + k] = s;
}

__global__ void k2_reduce(const float* __restrict__ pk2, float* __restrict__ k2) {
    int k = blockIdx.x * 256 + threadIdx.x;
    float s = 0.f;
    #pragma unroll
    for (int j = 0; j < 8; ++j) s += pk2[(size_t)j * K_ + k];
    k2[k] = s;
}

// ---------------- x2 = row sums of x^2 ----------------
__global__ void x2_kernel(const float* __restrict__ x, float* __restrict__ x2) {
    int row = blockIdx.x;
    const float* xr = x + (size_t)row * D_;
    int t = threadIdx.x;
    float4 v0 = ((const float4*)xr)[t];
    float4 v1 = ((const float4*)xr)[t + 256];
    float s = v0.x*v0.x + v0.y*v0.y + v0.z*v0.z + v0.w*v0.w
            + v1.x*v1.x + v1.y*v1.y + v1.z*v1.z + v1.w*v1.w;
    __shared__ float red[256];
    red[t] = s; __syncthreads();
    for (int off = 128; off > 0; off >>= 1) {
        if (t < off) red[t] += red[t + off];
        __syncthreads();
    }
    if (t == 0) x2[row] = red[0];
}

// ---------------- bf16 MFMA GEMM -> norms2 -> d_out ----------------
// 128x128 tile, BK=32 bf16, 4 waves (2x2), wave tile 64x64, 16x16x32 MFMA.
// Ah: [4096][2048] bf16 row-major; Bt: [16384][2048] bf16 row-major (kernel^T).
__global__ __launch_bounds__(256) void gemm_bf16(
    const short* __restrict__ Ah, const short* __restrict__ Bt,
    const float* __restrict__ x2, const float* __restrict__ k2,
    float* __restrict__ out)
{
    __shared__ short As[2][128 * 32];
    __shared__ short Bs[2][128 * 32];

    const int tid = threadIdx.x;
    const int bn0 = blockIdx.x * 128;
    const int bm0 = blockIdx.y * 128;
    const int w = tid >> 6, lane = tid & 63;
    const int wr = (w >> 1) * 64, wc = (w & 1) * 64;
    const int lrow = lane & 15, lkg = lane >> 4;

    // staging: thread covers LDS bytes tid*16 .. +16 of a tile half (64 rows)
    const int srow = tid >> 2, ks8 = (tid & 3) * 8;
    const short* gA0 = Ah + (size_t)(bm0 + srow) * 2048 + ks8;
    const short* gA1 = gA0 + (size_t)64 * 2048;
    const short* gB0 = Bt + (size_t)(bn0 + srow) * 2048 + ks8;
    const short* gB1 = gB0 + (size_t)64 * 2048;
    const int lds_off = tid * 8; // shorts

    f32x4 acc[4][4];
    #pragma unroll
    for (int i = 0; i < 4; ++i)
        #pragma unroll
        for (int j = 0; j < 4; ++j) acc[i][j] = (f32x4){0.f, 0.f, 0.f, 0.f};

    // fragment LDS element offsets
    int aoff[4], boff[4];
    #pragma unroll
    for (int f = 0; f < 4; ++f) {
        aoff[f] = (wr + f*16 + lrow) * 32 + lkg * 8;
        boff[f] = (wc + f*16 + lrow) * 32 + lkg * 8;
    }

    // prologue: stage tile 0 into buf 0
    gload16(gA0, &As[0][lds_off]);
    gload16(gA1, &As[0][2048 + lds_off]);
    gload16(gB0, &Bs[0][lds_off]);
    gload16(gB1, &Bs[0][2048 + lds_off]);

    const int NK = 2048 / 32;
    for (int kt = 0; kt < NK; ++kt) {
        const int cur = kt & 1;
        __syncthreads();   // drains vmcnt -> buf[cur] staged; prev ds_reads done

        if (kt + 1 < NK) {
            const int ko = (kt + 1) * 32;
            gload16(gA0 + ko, &As[cur ^ 1][lds_off]);
            gload16(gA1 + ko, &As[cur ^ 1][2048 + lds_off]);
            gload16(gB0 + ko, &Bs[cur ^ 1][lds_off]);
            gload16(gB1 + ko, &Bs[cur ^ 1][2048 + lds_off]);
        }

        bf16x8 af[4], bb[4];
        #pragma unroll
        for (int f = 0; f < 4; ++f) af[f] = *(const bf16x8*)&As[cur][aoff[f]];
        #pragma unroll
        for (int f = 0; f < 4; ++f) bb[f] = *(const bf16x8*)&Bs[cur][boff[f]];

        #pragma unroll
        for (int mf = 0; mf < 4; ++mf)
            #pragma unroll
            for (int nf = 0; nf < 4; ++nf)
                acc[mf][nf] = __builtin_amdgcn_mfma_f32_16x16x32_bf16(
                    af[mf], bb[nf], acc[mf][nf], 0, 0, 0);
    }

    // epilogue: norms2 = max(x2 - 2*dot + k2, 0); C/D layout: col=lane&15, row=(lane>>4)*4+j
    const int r0 = bm0 + wr + lkg * 4;
    const int c0 = bn0 + wc + lrow;
    float xrv[4][4];
    #pragma unroll
    for (int mf = 0; mf < 4; ++mf)
        #pragma unroll
        for (int j = 0; j < 4; ++j) xrv[mf][j] = x2[r0 + mf*16 + j];

    #pragma unroll
    for (int nf = 0; nf < 4; ++nf) {
        const int gc = c0 + nf * 16;
        const float kc = k2[gc];
        #pragma unroll
        for (int mf = 0; mf < 4; ++mf) {
            #pragma unroll
            for (int j = 0; j < 4; ++j) {
                const int gr = r0 + mf*16 + j;
                float vv = fmaxf((xrv[mf][j] - 2.f * acc[mf][nf][j]) + kc, 0.f);
                out[(size_t)gr * K_ + gc] = vv;
            }
        }
    }
}

// ---------------- f32 fallback GEMM (round-3, used if ws too small) ----------------
__global__ __launch_bounds__(256) void gemm_norms(
    const float* __restrict__ X, const float* __restrict__ Kmat,
    const float* __restrict__ x2, const float* __restrict__ k2,
    float* __restrict__ out)
{
    __shared__ float Asf[BD * ASTR];
    __shared__ float Bsf[BD * BN];

    const int tid = threadIdx.x;
    const int tx = tid & 15, ty = tid >> 4;
    const int bn0 = blockIdx.x * BN;
    const int bm0 = blockIdx.y * BM;

    float acc[8][8];
    #pragma unroll
    for (int i = 0; i < 8; ++i)
        #pragma unroll
        for (int j = 0; j < 8; ++j) acc[i][j] = 0.f;

    const int lm = tid >> 2;
    const int ld = (tid & 3) << 2;
    const int bd = tid >> 5;
    const int bk = (tid & 31) << 2;

    const float* Xp = X    + (size_t)(bm0 + lm) * D_ + ld;
    const float* Kp = Kmat + (size_t)bd * K_ + bn0 + bk;

    float4 a0 = *(const float4*)(Xp);
    float4 a1 = *(const float4*)(Xp + (size_t)64 * D_);
    float4 b0 = *(const float4*)(Kp);
    float4 b1 = *(const float4*)(Kp + (size_t)8 * K_);

    const int NT = D_ / BD;
    for (int kt = 0; kt < NT; ++kt) {
        __syncthreads();
        Asf[(ld+0)*ASTR + lm]      = a0.x;
        Asf[(ld+1)*ASTR + lm]      = a0.y;
        Asf[(ld+2)*ASTR + lm]      = a0.z;
        Asf[(ld+3)*ASTR + lm]      = a0.w;
        Asf[(ld+0)*ASTR + lm + 64] = a1.x;
        Asf[(ld+1)*ASTR + lm + 64] = a1.y;
        Asf[(ld+2)*ASTR + lm + 64] = a1.z;
        Asf[(ld+3)*ASTR + lm + 64] = a1.w;
        *(float4*)&Bsf[bd*BN + bk]     = b0;
        *(float4*)&Bsf[(bd+8)*BN + bk] = b1;
        __syncthreads();

        if (kt + 1 < NT) {
            const float* Xn = Xp + (kt + 1) * BD;
            const float* Kn = Kp + (size_t)(kt + 1) * BD * K_;
            a0 = *(const float4*)(Xn);
            a1 = *(const float4*)(Xn + (size_t)64 * D_);
            b0 = *(const float4*)(Kn);
            b1 = *(const float4*)(Kn + (size_t)8 * K_);
        }

        #pragma unroll
        for (int dd = 0; dd < BD; ++dd) {
            float4 A0 = *(const float4*)&Asf[dd*ASTR + ty*4];
            float4 A1 = *(const float4*)&Asf[dd*ASTR + ty*4 + 64];
            float4 B0 = *(const float4*)&Bsf[dd*BN + tx*4];
            float4 B1 = *(const float4*)&Bsf[dd*BN + tx*4 + 64];
            float a[8] = {A0.x,A0.y,A0.z,A0.w,A1.x,A1.y,A1.z,A1.w};
            float b[8] = {B0.x,B0.y,B0.z,B0.w,B1.x,B1.y,B1.z,B1.w};
            #pragma unroll
            for (int i = 0; i < 8; ++i)
                #pragma unroll
                for (int j = 0; j < 8; ++j)
                    acc[i][j] = fmaf(a[i], b[j], acc[i][j]);
        }
    }

    int rl[8], cl[8];
    #pragma unroll
    for (int i = 0; i < 4; ++i) {
        rl[i] = ty*4 + i;  rl[i+4] = ty*4 + 64 + i;
        cl[i] = tx*4 + i;  cl[i+4] = tx*4 + 64 + i;
    }
    float xr[8], kc[8];
    #pragma unroll
    for (int i = 0; i < 8; ++i) { xr[i] = x2[bm0 + rl[i]]; kc[i] = k2[bn0 + cl[i]]; }

    #pragma unroll
    for (int i = 0; i < 8; ++i) {
        float vv[8];
        #pragma unroll
        for (int j = 0; j < 8; ++j)
            vv[j] = fmaxf((xr[i] - 2.f * acc[i][j]) + kc[j], 0.f);
        int gr = bm0 + rl[i];
        *(float4*)&out[(size_t)gr * K_ + bn0 + tx*4]      = make_float4(vv[0],vv[1],vv[2],vv[3]);
        *(float4*)&out[(size_t)gr * K_ + bn0 + tx*4 + 64] = make_float4(vv[4],vv[5],vv[6],vv[7]);
    }
}

// ---------------- per-row argmin, emulating numpy's per-op f32-rounded pipeline ----------------
__global__ __launch_bounds__(256) void rowscan(
    const float* __restrict__ out, const float* __restrict__ X,
    const float* __restrict__ Kmat, int* __restrict__ widx)
{
    const int row = blockIdx.x;
    const int t = threadIdx.x;
    const float* orow = out + (size_t)row * K_;

    float mn = 3.4e38f;
    for (int i = t; i < K_/4; i += 256) {
        float4 v = ((const float4*)orow)[i];
        mn = fminf(mn, fminf(fminf(v.x, v.y), fminf(v.z, v.w)));
    }
    __shared__ float smin[256];
    smin[t] = mn; __syncthreads();
    for (int off = 128; off > 0; off >>= 1) {
        if (t < off) smin[t] = fminf(smin[t], smin[t+off]);
        __syncthreads();
    }
    const float rowmin = smin[0];

    __shared__ int scnt;
    __shared__ int cand[MAXCAND];
    if (t == 0) scnt = 0;
    __syncthreads();
    const float thr = rowmin + EPS_CAND;
    for (int i = t; i < K_/4; i += 256) {
        float4 v = ((const float4*)orow)[i];
        float vv[4] = {v.x, v.y, v.z, v.w};
        #pragma unroll
        for (int j = 0; j < 4; ++j) {
            if (vv[j] <= thr) {
                int p = atomicAdd(&scnt, 1);
                if (p < MAXCAND) cand[p] = i*4 + j;
            }
        }
    }
    __syncthreads();
    const int cnt = min(scnt, MAXCAND);
    if (cnt == 1) {
        if (t == 0) widx[row] = cand[0];
        return;
    }

    // refine with emulated-gold f32 scores (each primitive exact-f64 then f32-rounded)
    const float* xrow = X + (size_t)row * D_;
    __shared__ double sred[256];

    double xs = 0.0;
    for (int d = t; d < D_; d += 256) {
        float xv = xrow[d];
        float sq = xv * xv;
        xs += (double)sq;
    }
    sred[t] = xs; __syncthreads();
    for (int off = 128; off > 0; off >>= 1) {
        if (t < off) sred[t] += sred[t+off];
        __syncthreads();
    }
    const float x2f = (float)sred[0];
    __syncthreads();

    __shared__ float cscore[MAXCAND];
    for (int c = 0; c < cnt; ++c) {
        const int k = cand[c];
        double dt = 0.0, kk = 0.0;
        for (int d = t; d < D_; d += 256) {
            float w  = Kmat[(size_t)d * K_ + k];
            float xv = xrow[d];
            dt += (double)xv * (double)w;
            float w2 = w * w;
            kk += (double)w2;
        }
        sred[t] = dt; __syncthreads();
        for (int off = 128; off > 0; off >>= 1) {
            if (t < off) sred[t] += sred[t+off];
            __syncthreads();
        }
        const float dotf = (float)sred[0];
        __syncthreads();
        sred[t] = kk; __syncthreads();
        for (int off = 128; off > 0; off >>= 1) {
            if (t < off) sred[t] += sred[t+off];
            __syncthreads();
        }
        if (t == 0) {
            const float k2f = (float)sred[0];
            cscore[c] = fmaxf((x2f - 2.0f * dotf) + k2f, 0.0f);
        }
        __syncthreads();
    }
    if (t == 0) {
        float bv = cscore[0]; int bi = cand[0];
        for (int c = 1; c < cnt; ++c) {
            if (cscore[c] < bv || (cscore[c] == bv && cand[c] < bi)) {
                bv = cscore[c]; bi = cand[c];
            }
        }
        widx[row] = bi;
    }
}

// ---------------- finalize: out *= radials (in place) ----------------
__global__ void finalize(float* __restrict__ out, const int* __restrict__ widx,
                         const float* __restrict__ sigma) {
    size_t gid = (size_t)blockIdx.x * blockDim.x + threadIdx.x;
    int row = (int)(gid / (K_ / 4));
    int c4  = (int)(gid % (K_ / 4)) * 4;
    int w = widx[row];
    float wx = (float)(w >> 7), wy = (float)(w & 127);
    float sg = sigma[0];
    float ninv  = -0.5f / (sg * sg);
    float scale = 1.0f / (sg * sqrtf(2.0f * 3.14159265358979323846f));
    float4 v = *(float4*)&out[(size_t)row * K_ + c4];
    float* vp = (float*)&v;
    #pragma unroll
    for (int j = 0; j < 4; ++j) {
        int k = c4 + j;
        float gx = (float)(k >> 7), gy = (float)(k & 127);
        float dx = gx - wx, dy = gy - wy;
        float d2 = dx*dx + dy*dy;
        vp[j] = vp[j] * (__expf(ninv * d2) * scale);
    }
    *(float4*)&out[(size_t)row * K_ + c4] = v;
}

extern "C" void kernel_launch(void* const* d_in, const int* in_sizes, int n_in,
                              void* d_out, int out_size, void* d_ws, size_t ws_size,
                              hipStream_t stream) {
    const float* x     = (const float*)d_in[0];
    const float* kmat  = (const float*)d_in[1];
    const float* sigma = (const float*)d_in[2];
    float* out = (float*)d_out;

    const size_t BT_BYTES = (size_t)K_ * D_ * 2;   // 64 MB
    const size_t AH_BYTES = (size_t)B_ * D_ * 2;   // 16 MB
    const size_t WS_NEED  = BT_BYTES + AH_BYTES + (16384 + 4096 + 4096 + 8*16384) * 4;

    if (ws_size >= WS_NEED) {
        short* Bt  = (short*)d_ws;
        short* Ahp = (short*)((char*)d_ws + BT_BYTES);
        float* k2  = (float*)((char*)d_ws + BT_BYTES + AH_BYTES);
        float* x2  = k2 + 16384;
        int*   widx = (int*)(x2 + 4096);
        float* pk2 = (float*)(widx + 4096);

        pack_a   <<<4096, 256, 0, stream>>>(x, Ahp);
        pack_bt  <<<dim3(K_/64, D_/64), 256, 0, stream>>>(kmat, Bt);
        k2_partial<<<dim3(K_/256, 8), 256, 0, stream>>>(kmat, pk2);
        k2_reduce <<<K_/256, 256, 0, stream>>>(pk2, k2);
        x2_kernel <<<B_, 256, 0, stream>>>(x, x2);
        gemm_bf16 <<<dim3(K_/128, B_/128), 256, 0, stream>>>(Ahp, Bt, x2, k2, out);
        rowscan   <<<B_, 256, 0, stream>>>(out, x, kmat, widx);
        finalize  <<<(size_t)B_ * (K_/4) / 256, 256, 0, stream>>>(out, widx, sigma);
    } else {
        float* ws = (float*)d_ws;
        float* k2   = ws;
        float* x2   = ws + 16384;
        int*   widx = (int*)(ws + 20480);
        float* pk2  = ws + 24576;

        k2_partial<<<dim3(K_/256, 8), 256, 0, stream>>>(kmat, pk2);
        k2_reduce <<<K_/256, 256, 0, stream>>>(pk2, k2);
        x2_kernel <<<B_, 256, 0, stream>>>(x, x2);
        gemm_norms<<<dim3(K_/BN, B_/BM), 256, 0, stream>>>(x, kmat, x2, k2, out);
        rowscan   <<<B_, 256, 0, stream>>>(out, x, kmat, widx);
        finalize  <<<(size_t)B_ * (K_/4) / 256, 256, 0, stream>>>(out, widx, sigma);
    }
}

// Round 5
// 603.860 us; speedup vs baseline: 5.4524x; 1.2308x over previous
//
#include <hip/hip_runtime.h>
#include <math.h>

// Problem constants
#define B_    4096
#define D_    2048
#define K_    16384
#define SIDE  128

// f32-fallback GEMM tiling
#define BM 128
#define BN 128
#define BD 16
#define ASTR 132

// Argmin refinement
#define EPS_CAND 0.04f
#define MAXCAND  64

// 8-phase GEMM
#define NKT 32   // 2048 / 64

typedef __attribute__((ext_vector_type(8))) short bf16x8;
typedef __attribute__((ext_vector_type(4))) float f32x4;

__device__ __forceinline__ short bf16_rne(float f) {
    unsigned u = __float_as_uint(f);
    unsigned r = u + 0x7FFFu + ((u >> 16) & 1u);
    return (short)(r >> 16);
}

__device__ __forceinline__ void gload16(const void* g, void* l) {
    __builtin_amdgcn_global_load_lds(
        (const __attribute__((address_space(1))) unsigned int*)g,
        (__attribute__((address_space(3))) unsigned int*)l, 16, 0, 0);
}

// ---------------- pack x -> Ah (bf16, same layout) ----------------
__global__ __launch_bounds__(256) void pack_a(const float* __restrict__ x, short* __restrict__ Ah) {
    size_t i = ((size_t)blockIdx.x * 256 + threadIdx.x) * 8;
    float4 v0 = *(const float4*)&x[i];
    float4 v1 = *(const float4*)&x[i + 4];
    short tmp[8] = { bf16_rne(v0.x), bf16_rne(v0.y), bf16_rne(v0.z), bf16_rne(v0.w),
                     bf16_rne(v1.x), bf16_rne(v1.y), bf16_rne(v1.z), bf16_rne(v1.w) };
    *(int4*)&Ah[i] = *(const int4*)tmp;
}

// ---------------- pack kernel -> Bt (bf16, transposed [n][d]) ----------------
__global__ __launch_bounds__(256) void pack_bt(const float* __restrict__ kmat, short* __restrict__ Bt) {
    __shared__ float tile[64][65];
    const int n0 = blockIdx.x * 64, d0 = blockIdx.y * 64;
    const int t = threadIdx.x;
    const int lr = t >> 4, lc4 = (t & 15) * 4;
    #pragma unroll
    for (int r = 0; r < 4; ++r) {
        float4 v = *(const float4*)&kmat[(size_t)(d0 + lr + r*16) * K_ + n0 + lc4];
        tile[lr + r*16][lc4 + 0] = v.x;
        tile[lr + r*16][lc4 + 1] = v.y;
        tile[lr + r*16][lc4 + 2] = v.z;
        tile[lr + r*16][lc4 + 3] = v.w;
    }
    __syncthreads();
    const int n = t >> 2, dc = (t & 3) * 16;
    short tmp[16];
    #pragma unroll
    for (int i = 0; i < 16; ++i) tmp[i] = bf16_rne(tile[dc + i][n]);
    short* dst = &Bt[(size_t)(n0 + n) * 2048 + d0 + dc];
    *(int4*)dst       = *(const int4*)tmp;
    *(int4*)(dst + 8) = *(const int4*)(tmp + 8);
}

// ---------------- k2 = column sums of kernel^2 ----------------
__global__ void k2_partial(const float* __restrict__ kmat, float* __restrict__ pk2) {
    int k  = blockIdx.x * 256 + threadIdx.x;
    int d0 = blockIdx.y * 256;
    float s = 0.f;
    #pragma unroll 8
    for (int d = 0; d < 256; ++d) {
        float v = kmat[(size_t)(d0 + d) * K_ + k];
        s = fmaf(v, v, s);
    }
    pk2[(size_t)blockIdx.y * K_ + k] = s;
}

__global__ void k2_reduce(const float* __restrict__ pk2, float* __restrict__ k2) {
    int k = blockIdx.x * 256 + threadIdx.x;
    float s = 0.f;
    #pragma unroll
    for (int j = 0; j < 8; ++j) s += pk2[(size_t)j * K_ + k];
    k2[k] = s;
}

// ---------------- x2 = row sums of x^2 ----------------
__global__ void x2_kernel(const float* __restrict__ x, float* __restrict__ x2) {
    int row = blockIdx.x;
    const float* xr = x + (size_t)row * D_;
    int t = threadIdx.x;
    float4 v0 = ((const float4*)xr)[t];
    float4 v1 = ((const float4*)xr)[t + 256];
    float s = v0.x*v0.x + v0.y*v0.y + v0.z*v0.z + v0.w*v0.w
            + v1.x*v1.x + v1.y*v1.y + v1.z*v1.z + v1.w*v1.w;
    __shared__ float red[256];
    red[t] = s; __syncthreads();
    for (int off = 128; off > 0; off >>= 1) {
        if (t < off) red[t] += red[t + off];
        __syncthreads();
    }
    if (t == 0) x2[row] = red[0];
}

// ---------------- 8-phase 256x256 bf16 MFMA GEMM -> norms2 -> d_out ----------------
// LDS: [2 buf][2 ksub][256 rows][32 kcols] bf16 for A and B (128 KiB total).
// Per tile (BK=64): 4 phases (ksub x nh). Stage FIFO: P1:A-k1(t+1) P2:B-k1(t+1)
// P3:A-k0(t+2) P4:B-k0(t+2); vmcnt(4) once per tile at P4.
// Swizzle: LDS 16B-chunk c' = c ^ ((row>>1)&3); applied on the global source
// (gload dest linear) and on ds_read addresses (both-sides rule).
__global__ __launch_bounds__(512, 2) void gemm_8ph(
    const short* __restrict__ Ah, const short* __restrict__ Bt,
    const float* __restrict__ x2, const float* __restrict__ k2,
    float* __restrict__ out)
{
    __shared__ short As[4 * 8192];
    __shared__ short Bs[4 * 8192];

    const int tid = threadIdx.x;
    const int lane = tid & 63;
    const int w = tid >> 6;
    const int wm = w >> 2, wn = w & 3;
    const int lrow = lane & 15, lkg = lane >> 4;

    // XCD-aware swizzle: 1024 blocks = 8 xcds x (8 bn-chunk x 16 bm)
    const int orig = blockIdx.x;
    const int xcd = orig & 7, seq = orig >> 3;
    const int bn0 = (xcd * 8 + (seq & 7)) * 256;
    const int bm0 = (seq >> 3) * 256;

    // staging source (pre-swizzled chunk) : thread covers LDS bytes tid*16 of each 8KB inst
    const int csw = ((tid & 3) ^ ((tid >> 3) & 3)) * 8;   // shorts
    const short* pA = Ah + (size_t)(bm0 + (tid >> 2)) * 2048 + csw;
    const short* pB = Bt + (size_t)(bn0 + (tid >> 2)) * 2048 + csw;
    const int ldsT = tid * 8;  // shorts

    // fragment read bases (shorts) within a [256][32] region, with read-side swizzle
    const int rsw = (lkg ^ ((lrow >> 1) & 3)) * 8;
    const int aBase = (wm * 128 + lrow) * 32 + rsw;
    const int bBase = (wn * 64 + lrow) * 32 + rsw;

    f32x4 acc[8][4];
    #pragma unroll
    for (int i = 0; i < 8; ++i)
        #pragma unroll
        for (int j = 0; j < 4; ++j) acc[i][j] = (f32x4){0.f, 0.f, 0.f, 0.f};

#define STAGE(MATL, PTR, KS, T) do { \
    short* _l = (MATL) + ((((T) & 1) * 2 + (KS)) * 8192) + ldsT; \
    const short* _g = (PTR) + (size_t)(T) * 64 + (KS) * 32; \
    gload16(_g, _l); \
    gload16(_g + (size_t)128 * 2048, _l + 4096); \
} while (0)

#define PH_SYNC1 do { __builtin_amdgcn_sched_barrier(0); __builtin_amdgcn_s_barrier(); \
    asm volatile("s_waitcnt lgkmcnt(0)" ::: "memory"); __builtin_amdgcn_sched_barrier(0); \
    __builtin_amdgcn_s_setprio(1); } while (0)
#define PH_SYNC2 do { __builtin_amdgcn_s_setprio(0); __builtin_amdgcn_sched_barrier(0); \
    __builtin_amdgcn_s_barrier(); } while (0)

    // prologue: A-k0(0) B-k0(0) A-k1(0) B-k1(0) A-k0(1) B-k0(1); wait first 4 halves
    STAGE(As, pA, 0, 0); STAGE(Bs, pB, 0, 0);
    STAGE(As, pA, 1, 0); STAGE(Bs, pB, 1, 0);
    STAGE(As, pA, 0, 1); STAGE(Bs, pB, 0, 1);
    asm volatile("s_waitcnt vmcnt(4)" ::: "memory");
    __builtin_amdgcn_s_barrier();

    for (int t = 0; t < NKT; ++t) {
        const int rg = (t & 1) * 2;
        const short* Ar0 = &As[rg * 8192];
        const short* Br0 = &Bs[rg * 8192];
        const short* Ar1 = Ar0 + 8192;
        const short* Br1 = Br0 + 8192;
        bf16x8 a[8], b0, b1, b2, b3;

        // ---- P1: ksub0, nh0 ----
        #pragma unroll
        for (int mf = 0; mf < 8; ++mf) a[mf] = *(const bf16x8*)&Ar0[aBase + mf * 512];
        b0 = *(const bf16x8*)&Br0[bBase];
        b1 = *(const bf16x8*)&Br0[bBase + 512];
        if (t + 1 < NKT) STAGE(As, pA, 1, t + 1);
        PH_SYNC1;
        #pragma unroll
        for (int mf = 0; mf < 8; ++mf) {
            acc[mf][0] = __builtin_amdgcn_mfma_f32_16x16x32_bf16(a[mf], b0, acc[mf][0], 0, 0, 0);
            acc[mf][1] = __builtin_amdgcn_mfma_f32_16x16x32_bf16(a[mf], b1, acc[mf][1], 0, 0, 0);
        }
        PH_SYNC2;

        // ---- P2: ksub0, nh1 ----
        b2 = *(const bf16x8*)&Br0[bBase + 1024];
        b3 = *(const bf16x8*)&Br0[bBase + 1536];
        if (t + 1 < NKT) STAGE(Bs, pB, 1, t + 1);
        PH_SYNC1;
        #pragma unroll
        for (int mf = 0; mf < 8; ++mf) {
            acc[mf][2] = __builtin_amdgcn_mfma_f32_16x16x32_bf16(a[mf], b2, acc[mf][2], 0, 0, 0);
            acc[mf][3] = __builtin_amdgcn_mfma_f32_16x16x32_bf16(a[mf], b3, acc[mf][3], 0, 0, 0);
        }
        PH_SYNC2;

        // ---- P3: ksub1, nh0 ----
        #pragma unroll
        for (int mf = 0; mf < 8; ++mf) a[mf] = *(const bf16x8*)&Ar1[aBase + mf * 512];
        b0 = *(const bf16x8*)&Br1[bBase];
        b1 = *(const bf16x8*)&Br1[bBase + 512];
        if (t + 2 < NKT) STAGE(As, pA, 0, t + 2);
        PH_SYNC1;
        #pragma unroll
        for (int mf = 0; mf < 8; ++mf) {
            acc[mf][0] = __builtin_amdgcn_mfma_f32_16x16x32_bf16(a[mf], b0, acc[mf][0], 0, 0, 0);
            acc[mf][1] = __builtin_amdgcn_mfma_f32_16x16x32_bf16(a[mf], b1, acc[mf][1], 0, 0, 0);
        }
        PH_SYNC2;

        // ---- P4: ksub1, nh1 ----
        b2 = *(const bf16x8*)&Br1[bBase + 1024];
        b3 = *(const bf16x8*)&Br1[bBase + 1536];
        if (t + 2 < NKT) STAGE(Bs, pB, 0, t + 2);
        PH_SYNC1;
        #pragma unroll
        for (int mf = 0; mf < 8; ++mf) {
            acc[mf][2] = __builtin_amdgcn_mfma_f32_16x16x32_bf16(a[mf], b2, acc[mf][2], 0, 0, 0);
            acc[mf][3] = __builtin_amdgcn_mfma_f32_16x16x32_bf16(a[mf], b3, acc[mf][3], 0, 0, 0);
        }
        __builtin_amdgcn_s_setprio(0);
        __builtin_amdgcn_sched_barrier(0);
        asm volatile("s_waitcnt vmcnt(4)" ::: "memory");
        __builtin_amdgcn_s_barrier();
    }
#undef STAGE
#undef PH_SYNC1
#undef PH_SYNC2

    // epilogue: norms2 = max(x2 - 2*dot + k2, 0); C/D: col=lane&15, row=(lane>>4)*4+j
    const int r0 = bm0 + wm * 128 + lkg * 4;
    const int c0 = bn0 + wn * 64 + lrow;
    float kc[4];
    #pragma unroll
    for (int nf = 0; nf < 4; ++nf) kc[nf] = k2[c0 + nf * 16];
    #pragma unroll
    for (int mf = 0; mf < 8; ++mf) {
        #pragma unroll
        for (int jj = 0; jj < 4; ++jj) {
            const int gr = r0 + mf * 16 + jj;
            const float xv = x2[gr];
            float* orow = out + (size_t)gr * K_ + c0;
            #pragma unroll
            for (int nf = 0; nf < 4; ++nf) {
                float vv = fmaxf((xv - 2.f * acc[mf][nf][jj]) + kc[nf], 0.f);
                orow[nf * 16] = vv;
            }
        }
    }
}

// ---------------- f32 fallback GEMM (used if ws too small) ----------------
__global__ __launch_bounds__(256) void gemm_norms(
    const float* __restrict__ X, const float* __restrict__ Kmat,
    const float* __restrict__ x2, const float* __restrict__ k2,
    float* __restrict__ out)
{
    __shared__ float Asf[BD * ASTR];
    __shared__ float Bsf[BD * BN];

    const int tid = threadIdx.x;
    const int tx = tid & 15, ty = tid >> 4;
    const int bn0 = blockIdx.x * BN;
    const int bm0 = blockIdx.y * BM;

    float acc[8][8];
    #pragma unroll
    for (int i = 0; i < 8; ++i)
        #pragma unroll
        for (int j = 0; j < 8; ++j) acc[i][j] = 0.f;

    const int lm = tid >> 2;
    const int ld = (tid & 3) << 2;
    const int bd = tid >> 5;
    const int bk = (tid & 31) << 2;

    const float* Xp = X    + (size_t)(bm0 + lm) * D_ + ld;
    const float* Kp = Kmat + (size_t)bd * K_ + bn0 + bk;

    float4 a0 = *(const float4*)(Xp);
    float4 a1 = *(const float4*)(Xp + (size_t)64 * D_);
    float4 b0 = *(const float4*)(Kp);
    float4 b1 = *(const float4*)(Kp + (size_t)8 * K_);

    const int NT = D_ / BD;
    for (int kt = 0; kt < NT; ++kt) {
        __syncthreads();
        Asf[(ld+0)*ASTR + lm]      = a0.x;
        Asf[(ld+1)*ASTR + lm]      = a0.y;
        Asf[(ld+2)*ASTR + lm]      = a0.z;
        Asf[(ld+3)*ASTR + lm]      = a0.w;
        Asf[(ld+0)*ASTR + lm + 64] = a1.x;
        Asf[(ld+1)*ASTR + lm + 64] = a1.y;
        Asf[(ld+2)*ASTR + lm + 64] = a1.z;
        Asf[(ld+3)*ASTR + lm + 64] = a1.w;
        *(float4*)&Bsf[bd*BN + bk]     = b0;
        *(float4*)&Bsf[(bd+8)*BN + bk] = b1;
        __syncthreads();

        if (kt + 1 < NT) {
            const float* Xn = Xp + (kt + 1) * BD;
            const float* Kn = Kp + (size_t)(kt + 1) * BD * K_;
            a0 = *(const float4*)(Xn);
            a1 = *(const float4*)(Xn + (size_t)64 * D_);
            b0 = *(const float4*)(Kn);
            b1 = *(const float4*)(Kn + (size_t)8 * K_);
        }

        #pragma unroll
        for (int dd = 0; dd < BD; ++dd) {
            float4 A0 = *(const float4*)&Asf[dd*ASTR + ty*4];
            float4 A1 = *(const float4*)&Asf[dd*ASTR + ty*4 + 64];
            float4 B0 = *(const float4*)&Bsf[dd*BN + tx*4];
            float4 B1 = *(const float4*)&Bsf[dd*BN + tx*4 + 64];
            float a[8] = {A0.x,A0.y,A0.z,A0.w,A1.x,A1.y,A1.z,A1.w};
            float b[8] = {B0.x,B0.y,B0.z,B0.w,B1.x,B1.y,B1.z,B1.w};
            #pragma unroll
            for (int i = 0; i < 8; ++i)
                #pragma unroll
                for (int j = 0; j < 8; ++j)
                    acc[i][j] = fmaf(a[i], b[j], acc[i][j]);
        }
    }

    int rl[8], cl[8];
    #pragma unroll
    for (int i = 0; i < 4; ++i) {
        rl[i] = ty*4 + i;  rl[i+4] = ty*4 + 64 + i;
        cl[i] = tx*4 + i;  cl[i+4] = tx*4 + 64 + i;
    }
    float xr[8], kc[8];
    #pragma unroll
    for (int i = 0; i < 8; ++i) { xr[i] = x2[bm0 + rl[i]]; kc[i] = k2[bn0 + cl[i]]; }

    #pragma unroll
    for (int i = 0; i < 8; ++i) {
        float vv[8];
        #pragma unroll
        for (int j = 0; j < 8; ++j)
            vv[j] = fmaxf((xr[i] - 2.f * acc[i][j]) + kc[j], 0.f);
        int gr = bm0 + rl[i];
        *(float4*)&out[(size_t)gr * K_ + bn0 + tx*4]      = make_float4(vv[0],vv[1],vv[2],vv[3]);
        *(float4*)&out[(size_t)gr * K_ + bn0 + tx*4 + 64] = make_float4(vv[4],vv[5],vv[6],vv[7]);
    }
}

// ---------------- per-row argmin, emulating numpy's per-op f32-rounded pipeline ----------------
__global__ __launch_bounds__(256) void rowscan(
    const float* __restrict__ out, const float* __restrict__ X,
    const float* __restrict__ Kmat, int* __restrict__ widx)
{
    const int row = blockIdx.x;
    const int t = threadIdx.x;
    const float* orow = out + (size_t)row * K_;

    float mn = 3.4e38f;
    for (int i = t; i < K_/4; i += 256) {
        float4 v = ((const float4*)orow)[i];
        mn = fminf(mn, fminf(fminf(v.x, v.y), fminf(v.z, v.w)));
    }
    __shared__ float smin[256];
    smin[t] = mn; __syncthreads();
    for (int off = 128; off > 0; off >>= 1) {
        if (t < off) smin[t] = fminf(smin[t], smin[t+off]);
        __syncthreads();
    }
    const float rowmin = smin[0];

    __shared__ int scnt;
    __shared__ int cand[MAXCAND];
    if (t == 0) scnt = 0;
    __syncthreads();
    const float thr = rowmin + EPS_CAND;
    for (int i = t; i < K_/4; i += 256) {
        float4 v = ((const float4*)orow)[i];
        float vv[4] = {v.x, v.y, v.z, v.w};
        #pragma unroll
        for (int j = 0; j < 4; ++j) {
            if (vv[j] <= thr) {
                int p = atomicAdd(&scnt, 1);
                if (p < MAXCAND) cand[p] = i*4 + j;
            }
        }
    }
    __syncthreads();
    const int cnt = min(scnt, MAXCAND);
    if (cnt == 1) {
        if (t == 0) widx[row] = cand[0];
        return;
    }

    // refine with emulated-gold f32 scores (each primitive exact-f64 then f32-rounded)
    const float* xrow = X + (size_t)row * D_;
    __shared__ double sred[256];

    double xs = 0.0;
    for (int d = t; d < D_; d += 256) {
        float xv = xrow[d];
        float sq = xv * xv;
        xs += (double)sq;
    }
    sred[t] = xs; __syncthreads();
    for (int off = 128; off > 0; off >>= 1) {
        if (t < off) sred[t] += sred[t+off];
        __syncthreads();
    }
    const float x2f = (float)sred[0];
    __syncthreads();

    __shared__ float cscore[MAXCAND];
    for (int c = 0; c < cnt; ++c) {
        const int k = cand[c];
        double dt = 0.0, kk = 0.0;
        for (int d = t; d < D_; d += 256) {
            float w  = Kmat[(size_t)d * K_ + k];
            float xv = xrow[d];
            dt += (double)xv * (double)w;
            float w2 = w * w;
            kk += (double)w2;
        }
        sred[t] = dt; __syncthreads();
        for (int off = 128; off > 0; off >>= 1) {
            if (t < off) sred[t] += sred[t+off];
            __syncthreads();
        }
        const float dotf = (float)sred[0];
        __syncthreads();
        sred[t] = kk; __syncthreads();
        for (int off = 128; off > 0; off >>= 1) {
            if (t < off) sred[t] += sred[t+off];
            __syncthreads();
        }
        if (t == 0) {
            const float k2f = (float)sred[0];
            cscore[c] = fmaxf((x2f - 2.0f * dotf) + k2f, 0.0f);
        }
        __syncthreads();
    }
    if (t == 0) {
        float bv = cscore[0]; int bi = cand[0];
        for (int c = 1; c < cnt; ++c) {
            if (cscore[c] < bv || (cscore[c] == bv && cand[c] < bi)) {
                bv = cscore[c]; bi = cand[c];
            }
        }
        widx[row] = bi;
    }
}

// ---------------- finalize: out *= radials (in place) ----------------
__global__ void finalize(float* __restrict__ out, const int* __restrict__ widx,
                         const float* __restrict__ sigma) {
    size_t gid = (size_t)blockIdx.x * blockDim.x + threadIdx.x;
    int row = (int)(gid / (K_ / 4));
    int c4  = (int)(gid % (K_ / 4)) * 4;
    int w = widx[row];
    float wx = (float)(w >> 7), wy = (float)(w & 127);
    float sg = sigma[0];
    float ninv  = -0.5f / (sg * sg);
    float scale = 1.0f / (sg * sqrtf(2.0f * 3.14159265358979323846f));
    float4 v = *(float4*)&out[(size_t)row * K_ + c4];
    float* vp = (float*)&v;
    #pragma unroll
    for (int j = 0; j < 4; ++j) {
        int k = c4 + j;
        float gx = (float)(k >> 7), gy = (float)(k & 127);
        float dx = gx - wx, dy = gy - wy;
        float d2 = dx*dx + dy*dy;
        vp[j] = vp[j] * (__expf(ninv * d2) * scale);
    }
    *(float4*)&out[(size_t)row * K_ + c4] = v;
}

extern "C" void kernel_launch(void* const* d_in, const int* in_sizes, int n_in,
                              void* d_out, int out_size, void* d_ws, size_t ws_size,
                              hipStream_t stream) {
    const float* x     = (const float*)d_in[0];
    const float* kmat  = (const float*)d_in[1];
    const float* sigma = (const float*)d_in[2];
    float* out = (float*)d_out;

    const size_t BT_BYTES = (size_t)K_ * D_ * 2;   // 64 MB
    const size_t AH_BYTES = (size_t)B_ * D_ * 2;   // 16 MB
    const size_t WS_NEED  = BT_BYTES + AH_BYTES + (16384 + 4096 + 4096 + 8*16384) * 4;

    if (ws_size >= WS_NEED) {
        short* Bt  = (short*)d_ws;
        short* Ahp = (short*)((char*)d_ws + BT_BYTES);
        float* k2  = (float*)((char*)d_ws + BT_BYTES + AH_BYTES);
        float* x2  = k2 + 16384;
        int*   widx = (int*)(x2 + 4096);
        float* pk2 = (float*)(widx + 4096);

        pack_a   <<<4096, 256, 0, stream>>>(x, Ahp);
        pack_bt  <<<dim3(K_/64, D_/64), 256, 0, stream>>>(kmat, Bt);
        k2_partial<<<dim3(K_/256, 8), 256, 0, stream>>>(kmat, pk2);
        k2_reduce <<<K_/256, 256, 0, stream>>>(pk2, k2);
        x2_kernel <<<B_, 256, 0, stream>>>(x, x2);
        gemm_8ph  <<<1024, 512, 0, stream>>>(Ahp, Bt, x2, k2, out);
        rowscan   <<<B_, 256, 0, stream>>>(out, x, kmat, widx);
        finalize  <<<(size_t)B_ * (K_/4) / 256, 256, 0, stream>>>(out, widx, sigma);
    } else {
        float* ws = (float*)d_ws;
        float* k2   = ws;
        float* x2   = ws + 16384;
        int*   widx = (int*)(ws + 20480);
        float* pk2  = ws + 24576;

        k2_partial<<<dim3(K_/256, 8), 256, 0, stream>>>(kmat, pk2);
        k2_reduce <<<K_/256, 256, 0, stream>>>(pk2, k2);
        x2_kernel <<<B_, 256, 0, stream>>>(x, x2);
        gemm_norms<<<dim3(K_/BN, B_/BM), 256, 0, stream>>>(x, kmat, x2, k2, out);
        rowscan   <<<B_, 256, 0, stream>>>(out, x, kmat, widx);
        finalize  <<<(size_t)B_ * (K_/4) / 256, 256, 0, stream>>>(out, widx, sigma);
    }
}

// Round 6
// 551.984 us; speedup vs baseline: 5.9649x; 1.0940x over previous
//
#include <hip/hip_runtime.h>
#include <math.h>

// Problem constants
#define B_    4096
#define D_    2048
#define K_    16384
#define SIDE  128

// f32-fallback GEMM tiling
#define BM 128
#define BN 128
#define BD 16
#define ASTR 132

// Argmin refinement
#define EPS_CAND 0.04f
#define MAXCAND  64

// 8-phase GEMM
#define NKT 32   // 2048 / 64

typedef __attribute__((ext_vector_type(8))) short bf16x8;
typedef __attribute__((ext_vector_type(4))) float f32x4;

__device__ __forceinline__ short bf16_rne(float f) {
    unsigned u = __float_as_uint(f);
    unsigned r = u + 0x7FFFu + ((u >> 16) & 1u);
    return (short)(r >> 16);
}

__device__ __forceinline__ void gload16(const void* g, void* l) {
    __builtin_amdgcn_global_load_lds(
        (const __attribute__((address_space(1))) unsigned int*)g,
        (__attribute__((address_space(3))) unsigned int*)l, 16, 0, 0);
}

// ---------------- pack x -> Ah (bf16) + x2 row sums, fused ----------------
__global__ __launch_bounds__(256) void pack_a_x2(const float* __restrict__ x,
                                                 short* __restrict__ Ah,
                                                 float* __restrict__ x2) {
    const int row = blockIdx.x;
    const int t = threadIdx.x;
    const size_t i = (size_t)row * 2048 + (size_t)t * 8;
    float4 v0 = *(const float4*)&x[i];
    float4 v1 = *(const float4*)&x[i + 4];
    short tmp[8] = { bf16_rne(v0.x), bf16_rne(v0.y), bf16_rne(v0.z), bf16_rne(v0.w),
                     bf16_rne(v1.x), bf16_rne(v1.y), bf16_rne(v1.z), bf16_rne(v1.w) };
    *(int4*)&Ah[i] = *(const int4*)tmp;
    float s = v0.x*v0.x + v0.y*v0.y + v0.z*v0.z + v0.w*v0.w
            + v1.x*v1.x + v1.y*v1.y + v1.z*v1.z + v1.w*v1.w;
    __shared__ float red[256];
    red[t] = s; __syncthreads();
    for (int off = 128; off > 0; off >>= 1) {
        if (t < off) red[t] += red[t + off];
        __syncthreads();
    }
    if (t == 0) x2[row] = red[0];
}

// ---------------- pack kernel -> Bt (bf16 transposed) + k2 partials, fused ----------------
__global__ __launch_bounds__(256) void pack_bt_k2(const float* __restrict__ kmat,
                                                  short* __restrict__ Bt,
                                                  float* __restrict__ pk2b) {
    __shared__ float tile[64][65];
    const int n0 = blockIdx.x * 64, d0 = blockIdx.y * 64;
    const int t = threadIdx.x;
    const int lr = t >> 4, lc4 = (t & 15) * 4;
    #pragma unroll
    for (int r = 0; r < 4; ++r) {
        float4 v = *(const float4*)&kmat[(size_t)(d0 + lr + r*16) * K_ + n0 + lc4];
        tile[lr + r*16][lc4 + 0] = v.x;
        tile[lr + r*16][lc4 + 1] = v.y;
        tile[lr + r*16][lc4 + 2] = v.z;
        tile[lr + r*16][lc4 + 3] = v.w;
    }
    __syncthreads();
    const int n = t >> 2, dc = (t & 3) * 16;
    short tmp[16];
    float s = 0.f;
    #pragma unroll
    for (int i = 0; i < 16; ++i) {
        float v = tile[dc + i][n];
        tmp[i] = bf16_rne(v);
        s = fmaf(v, v, s);
    }
    short* dst = &Bt[(size_t)(n0 + n) * 2048 + d0 + dc];
    *(int4*)dst       = *(const int4*)tmp;
    *(int4*)(dst + 8) = *(const int4*)(tmp + 8);
    // deterministic 4-way reduce across the threads sharing column n
    s += __shfl_xor(s, 1);
    s += __shfl_xor(s, 2);
    if ((t & 3) == 0) pk2b[(size_t)(d0 >> 6) * K_ + n0 + n] = s;
}

__global__ void k2_reduce32(const float* __restrict__ pk2b, float* __restrict__ k2) {
    int k = blockIdx.x * 256 + threadIdx.x;
    float s = 0.f;
    #pragma unroll
    for (int j = 0; j < 32; ++j) s += pk2b[(size_t)j * K_ + k];
    k2[k] = s;
}

// ---------------- 8-phase 256x256 bf16 MFMA GEMM -> norms2 -> d_out + pmin ----------------
__global__ __launch_bounds__(512, 2) void gemm_8ph(
    const short* __restrict__ Ah, const short* __restrict__ Bt,
    const float* __restrict__ x2, const float* __restrict__ k2,
    float* __restrict__ out, float* __restrict__ pmin)
{
    __shared__ short As[4 * 8192];
    __shared__ short Bs[4 * 8192];

    const int tid = threadIdx.x;
    const int lane = tid & 63;
    const int w = tid >> 6;
    const int wm = w >> 2, wn = w & 3;
    const int lrow = lane & 15, lkg = lane >> 4;

    // XCD-aware swizzle: 1024 blocks = 8 xcds x (8 bn-chunk x 16 bm)
    const int orig = blockIdx.x;
    const int xcd = orig & 7, seq = orig >> 3;
    const int bn0 = (xcd * 8 + (seq & 7)) * 256;
    const int bm0 = (seq >> 3) * 256;

    const int csw = ((tid & 3) ^ ((tid >> 3) & 3)) * 8;   // pre-swizzled source chunk
    const short* pA = Ah + (size_t)(bm0 + (tid >> 2)) * 2048 + csw;
    const short* pB = Bt + (size_t)(bn0 + (tid >> 2)) * 2048 + csw;
    const int ldsT = tid * 8;

    const int rsw = (lkg ^ ((lrow >> 1) & 3)) * 8;        // read-side swizzle
    const int aBase = (wm * 128 + lrow) * 32 + rsw;
    const int bBase = (wn * 64 + lrow) * 32 + rsw;

    f32x4 acc[8][4];
    #pragma unroll
    for (int i = 0; i < 8; ++i)
        #pragma unroll
        for (int j = 0; j < 4; ++j) acc[i][j] = (f32x4){0.f, 0.f, 0.f, 0.f};

#define STAGE(MATL, PTR, KS, T) do { \
    short* _l = (MATL) + ((((T) & 1) * 2 + (KS)) * 8192) + ldsT; \
    const short* _g = (PTR) + (size_t)(T) * 64 + (KS) * 32; \
    gload16(_g, _l); \
    gload16(_g + (size_t)128 * 2048, _l + 4096); \
} while (0)

#define PH_SYNC1 do { __builtin_amdgcn_sched_barrier(0); __builtin_amdgcn_s_barrier(); \
    asm volatile("s_waitcnt lgkmcnt(0)" ::: "memory"); __builtin_amdgcn_sched_barrier(0); \
    __builtin_amdgcn_s_setprio(1); } while (0)
#define PH_SYNC2 do { __builtin_amdgcn_s_setprio(0); __builtin_amdgcn_sched_barrier(0); \
    __builtin_amdgcn_s_barrier(); } while (0)

    STAGE(As, pA, 0, 0); STAGE(Bs, pB, 0, 0);
    STAGE(As, pA, 1, 0); STAGE(Bs, pB, 1, 0);
    STAGE(As, pA, 0, 1); STAGE(Bs, pB, 0, 1);
    asm volatile("s_waitcnt vmcnt(4)" ::: "memory");
    __builtin_amdgcn_s_barrier();

    for (int t = 0; t < NKT; ++t) {
        const int rg = (t & 1) * 2;
        const short* Ar0 = &As[rg * 8192];
        const short* Br0 = &Bs[rg * 8192];
        const short* Ar1 = Ar0 + 8192;
        const short* Br1 = Br0 + 8192;
        bf16x8 a[8], b0, b1, b2, b3;

        // ---- P1: ksub0, nh0 ----
        #pragma unroll
        for (int mf = 0; mf < 8; ++mf) a[mf] = *(const bf16x8*)&Ar0[aBase + mf * 512];
        b0 = *(const bf16x8*)&Br0[bBase];
        b1 = *(const bf16x8*)&Br0[bBase + 512];
        if (t + 1 < NKT) STAGE(As, pA, 1, t + 1);
        PH_SYNC1;
        #pragma unroll
        for (int mf = 0; mf < 8; ++mf) {
            acc[mf][0] = __builtin_amdgcn_mfma_f32_16x16x32_bf16(a[mf], b0, acc[mf][0], 0, 0, 0);
            acc[mf][1] = __builtin_amdgcn_mfma_f32_16x16x32_bf16(a[mf], b1, acc[mf][1], 0, 0, 0);
        }
        PH_SYNC2;

        // ---- P2: ksub0, nh1 ----
        b2 = *(const bf16x8*)&Br0[bBase + 1024];
        b3 = *(const bf16x8*)&Br0[bBase + 1536];
        if (t + 1 < NKT) STAGE(Bs, pB, 1, t + 1);
        PH_SYNC1;
        #pragma unroll
        for (int mf = 0; mf < 8; ++mf) {
            acc[mf][2] = __builtin_amdgcn_mfma_f32_16x16x32_bf16(a[mf], b2, acc[mf][2], 0, 0, 0);
            acc[mf][3] = __builtin_amdgcn_mfma_f32_16x16x32_bf16(a[mf], b3, acc[mf][3], 0, 0, 0);
        }
        PH_SYNC2;

        // ---- P3: ksub1, nh0 ----
        #pragma unroll
        for (int mf = 0; mf < 8; ++mf) a[mf] = *(const bf16x8*)&Ar1[aBase + mf * 512];
        b0 = *(const bf16x8*)&Br1[bBase];
        b1 = *(const bf16x8*)&Br1[bBase + 512];
        if (t + 2 < NKT) STAGE(As, pA, 0, t + 2);
        PH_SYNC1;
        #pragma unroll
        for (int mf = 0; mf < 8; ++mf) {
            acc[mf][0] = __builtin_amdgcn_mfma_f32_16x16x32_bf16(a[mf], b0, acc[mf][0], 0, 0, 0);
            acc[mf][1] = __builtin_amdgcn_mfma_f32_16x16x32_bf16(a[mf], b1, acc[mf][1], 0, 0, 0);
        }
        PH_SYNC2;

        // ---- P4: ksub1, nh1 ----
        b2 = *(const bf16x8*)&Br1[bBase + 1024];
        b3 = *(const bf16x8*)&Br1[bBase + 1536];
        if (t + 2 < NKT) STAGE(Bs, pB, 0, t + 2);
        PH_SYNC1;
        #pragma unroll
        for (int mf = 0; mf < 8; ++mf) {
            acc[mf][2] = __builtin_amdgcn_mfma_f32_16x16x32_bf16(a[mf], b2, acc[mf][2], 0, 0, 0);
            acc[mf][3] = __builtin_amdgcn_mfma_f32_16x16x32_bf16(a[mf], b3, acc[mf][3], 0, 0, 0);
        }
        __builtin_amdgcn_s_setprio(0);
        __builtin_amdgcn_sched_barrier(0);
        asm volatile("s_waitcnt vmcnt(4)" ::: "memory");
        __builtin_amdgcn_s_barrier();
    }
#undef STAGE
#undef PH_SYNC1
#undef PH_SYNC2

    // ---- epilogue: norms2 -> LDS repack -> float4 stores + per-row-block min ----
    // C/D frag: col = lane&15, row = (lane>>4)*4 + j
    const int c0 = bn0 + wn * 64 + lrow;
    float kc[4];
    #pragma unroll
    for (int nf = 0; nf < 4; ++nf) kc[nf] = k2[c0 + nf * 16];

    float* ldsF = (float*)As;   // 64 KB scratch: one 64x256 f32 chunk
    const int bnBlk = bn0 >> 8;
    __syncthreads();

    #pragma unroll
    for (int chunk = 0; chunk < 4; ++chunk) {
        if (wm == (chunk >> 1)) {
            const int mf0 = (chunk & 1) * 4;
            #pragma unroll
            for (int mfi = 0; mfi < 4; ++mfi) {
                #pragma unroll
                for (int jj = 0; jj < 4; ++jj) {
                    const int rl = mfi * 16 + lkg * 4 + jj;
                    const float xv = x2[bm0 + chunk * 64 + rl];
                    #pragma unroll
                    for (int nf = 0; nf < 4; ++nf)
                        ldsF[rl * 256 + wn * 64 + nf * 16 + lrow] =
                            fmaxf((xv - 2.f * acc[mf0 + mfi][nf][jj]) + kc[nf], 0.f);
                }
            }
        }
        __syncthreads();
        // coalesced float4 stream-out
        #pragma unroll
        for (int i = 0; i < 8; ++i) {
            const int f = tid + i * 512;
            const int rl = f >> 6, cc = (f & 63) * 4;
            *(float4*)&out[(size_t)(bm0 + chunk * 64 + rl) * K_ + bn0 + cc] =
                *(const float4*)&ldsF[rl * 256 + cc];
        }
        // per-row min over this block's 256 cols
        {
            const int r8 = tid >> 3, sg = tid & 7;
            float m = 3.4e38f;
            #pragma unroll
            for (int i = 0; i < 8; ++i) {
                float4 v = *(const float4*)&ldsF[r8 * 256 + sg * 32 + i * 4];
                m = fminf(m, fminf(fminf(v.x, v.y), fminf(v.z, v.w)));
            }
            m = fminf(m, __shfl_xor(m, 1));
            m = fminf(m, __shfl_xor(m, 2));
            m = fminf(m, __shfl_xor(m, 4));
            if (sg == 0) pmin[(size_t)(bm0 + chunk * 64 + r8) * 64 + bnBlk] = m;
        }
        __syncthreads();
    }
}

// ---------------- fused rowscan + finalize ----------------
__global__ __launch_bounds__(256) void rowpost(
    float* __restrict__ out, const float* __restrict__ X,
    const float* __restrict__ Kmat, const float* __restrict__ pmin,
    const float* __restrict__ sigma)
{
    const int row = blockIdx.x;
    const int t = threadIdx.x;
    float* orow = out + (size_t)row * K_;

    // rowmin from pmin (exact min of stored values)
    __shared__ float sminb[64];
    __shared__ float srowmin;
    if (t < 64) sminb[t] = pmin[(size_t)row * 64 + t];
    __syncthreads();
    if (t == 0) {
        float m = sminb[0];
        for (int i = 1; i < 64; ++i) m = fminf(m, sminb[i]);
        srowmin = m;
    }
    __syncthreads();
    const float rowmin = srowmin;

    // candidate collection (single HBM pass over the row)
    __shared__ int scnt;
    __shared__ int cand[MAXCAND];
    __shared__ int swidx;
    if (t == 0) scnt = 0;
    __syncthreads();
    const float thr = rowmin + EPS_CAND;
    for (int i = t; i < K_/4; i += 256) {
        float4 v = ((const float4*)orow)[i];
        float vv[4] = {v.x, v.y, v.z, v.w};
        #pragma unroll
        for (int j = 0; j < 4; ++j) {
            if (vv[j] <= thr) {
                int p = atomicAdd(&scnt, 1);
                if (p < MAXCAND) cand[p] = i*4 + j;
            }
        }
    }
    __syncthreads();
    const int cnt = min(scnt, MAXCAND);

    if (cnt == 1) {
        if (t == 0) swidx = cand[0];
    } else {
        // refine with emulated-gold f32 scores (exact-f64 per primitive, then f32 round)
        const float* xrow = X + (size_t)row * D_;
        __shared__ double sred[256];
        double xs = 0.0;
        for (int d = t; d < D_; d += 256) {
            float xv = xrow[d];
            float sq = xv * xv;
            xs += (double)sq;
        }
        sred[t] = xs; __syncthreads();
        for (int off = 128; off > 0; off >>= 1) {
            if (t < off) sred[t] += sred[t+off];
            __syncthreads();
        }
        const float x2f = (float)sred[0];
        __syncthreads();

        __shared__ float cscore[MAXCAND];
        for (int c = 0; c < cnt; ++c) {
            const int k = cand[c];
            double dt = 0.0, kk = 0.0;
            for (int d = t; d < D_; d += 256) {
                float wv = Kmat[(size_t)d * K_ + k];
                float xv = xrow[d];
                dt += (double)xv * (double)wv;
                float w2 = wv * wv;
                kk += (double)w2;
            }
            sred[t] = dt; __syncthreads();
            for (int off = 128; off > 0; off >>= 1) {
                if (t < off) sred[t] += sred[t+off];
                __syncthreads();
            }
            const float dotf = (float)sred[0];
            __syncthreads();
            sred[t] = kk; __syncthreads();
            for (int off = 128; off > 0; off >>= 1) {
                if (t < off) sred[t] += sred[t+off];
                __syncthreads();
            }
            if (t == 0) {
                const float k2f = (float)sred[0];
                cscore[c] = fmaxf((x2f - 2.0f * dotf) + k2f, 0.0f);
            }
            __syncthreads();
        }
        if (t == 0) {
            float bv = cscore[0]; int bi = cand[0];
            for (int c = 1; c < cnt; ++c) {
                if (cscore[c] < bv || (cscore[c] == bv && cand[c] < bi)) {
                    bv = cscore[c]; bi = cand[c];
                }
            }
            swidx = bi;
        }
    }
    __syncthreads();

    // finalize: radial multiply (row is L2-hot from the candidate pass)
    const int wi = swidx;
    const float wx = (float)(wi >> 7), wy = (float)(wi & 127);
    const float sg = sigma[0];
    const float ninv  = -0.5f / (sg * sg);
    const float scale = 1.0f / (sg * sqrtf(2.0f * 3.14159265358979323846f));
    for (int i = t; i < K_/4; i += 256) {
        float4 v = ((const float4*)orow)[i];
        float* vp = (float*)&v;
        #pragma unroll
        for (int j = 0; j < 4; ++j) {
            int k = i*4 + j;
            float gx = (float)(k >> 7), gy = (float)(k & 127);
            float dx = gx - wx, dy = gy - wy;
            float d2 = dx*dx + dy*dy;
            vp[j] = vp[j] * (__expf(ninv * d2) * scale);
        }
        ((float4*)orow)[i] = v;
    }
}

// ================= f32 fallback path (unchanged round-3 kernels) =================
__global__ void k2_partial(const float* __restrict__ kmat, float* __restrict__ pk2) {
    int k  = blockIdx.x * 256 + threadIdx.x;
    int d0 = blockIdx.y * 256;
    float s = 0.f;
    #pragma unroll 8
    for (int d = 0; d < 256; ++d) {
        float v = kmat[(size_t)(d0 + d) * K_ + k];
        s = fmaf(v, v, s);
    }
    pk2[(size_t)blockIdx.y * K_ + k] = s;
}

__global__ void k2_reduce(const float* __restrict__ pk2, float* __restrict__ k2) {
    int k = blockIdx.x * 256 + threadIdx.x;
    float s = 0.f;
    #pragma unroll
    for (int j = 0; j < 8; ++j) s += pk2[(size_t)j * K_ + k];
    k2[k] = s;
}

__global__ void x2_kernel(const float* __restrict__ x, float* __restrict__ x2) {
    int row = blockIdx.x;
    const float* xr = x + (size_t)row * D_;
    int t = threadIdx.x;
    float4 v0 = ((const float4*)xr)[t];
    float4 v1 = ((const float4*)xr)[t + 256];
    float s = v0.x*v0.x + v0.y*v0.y + v0.z*v0.z + v0.w*v0.w
            + v1.x*v1.x + v1.y*v1.y + v1.z*v1.z + v1.w*v1.w;
    __shared__ float red[256];
    red[t] = s; __syncthreads();
    for (int off = 128; off > 0; off >>= 1) {
        if (t < off) red[t] += red[t + off];
        __syncthreads();
    }
    if (t == 0) x2[row] = red[0];
}

__global__ __launch_bounds__(256) void gemm_norms(
    const float* __restrict__ X, const float* __restrict__ Kmat,
    const float* __restrict__ x2, const float* __restrict__ k2,
    float* __restrict__ out)
{
    __shared__ float Asf[BD * ASTR];
    __shared__ float Bsf[BD * BN];

    const int tid = threadIdx.x;
    const int tx = tid & 15, ty = tid >> 4;
    const int bn0 = blockIdx.x * BN;
    const int bm0 = blockIdx.y * BM;

    float acc[8][8];
    #pragma unroll
    for (int i = 0; i < 8; ++i)
        #pragma unroll
        for (int j = 0; j < 8; ++j) acc[i][j] = 0.f;

    const int lm = tid >> 2;
    const int ld = (tid & 3) << 2;
    const int bd = tid >> 5;
    const int bk = (tid & 31) << 2;

    const float* Xp = X    + (size_t)(bm0 + lm) * D_ + ld;
    const float* Kp = Kmat + (size_t)bd * K_ + bn0 + bk;

    float4 a0 = *(const float4*)(Xp);
    float4 a1 = *(const float4*)(Xp + (size_t)64 * D_);
    float4 b0 = *(const float4*)(Kp);
    float4 b1 = *(const float4*)(Kp + (size_t)8 * K_);

    const int NT = D_ / BD;
    for (int kt = 0; kt < NT; ++kt) {
        __syncthreads();
        Asf[(ld+0)*ASTR + lm]      = a0.x;
        Asf[(ld+1)*ASTR + lm]      = a0.y;
        Asf[(ld+2)*ASTR + lm]      = a0.z;
        Asf[(ld+3)*ASTR + lm]      = a0.w;
        Asf[(ld+0)*ASTR + lm + 64] = a1.x;
        Asf[(ld+1)*ASTR + lm + 64] = a1.y;
        Asf[(ld+2)*ASTR + lm + 64] = a1.z;
        Asf[(ld+3)*ASTR + lm + 64] = a1.w;
        *(float4*)&Bsf[bd*BN + bk]     = b0;
        *(float4*)&Bsf[(bd+8)*BN + bk] = b1;
        __syncthreads();

        if (kt + 1 < NT) {
            const float* Xn = Xp + (kt + 1) * BD;
            const float* Kn = Kp + (size_t)(kt + 1) * BD * K_;
            a0 = *(const float4*)(Xn);
            a1 = *(const float4*)(Xn + (size_t)64 * D_);
            b0 = *(const float4*)(Kn);
            b1 = *(const float4*)(Kn + (size_t)8 * K_);
        }

        #pragma unroll
        for (int dd = 0; dd < BD; ++dd) {
            float4 A0 = *(const float4*)&Asf[dd*ASTR + ty*4];
            float4 A1 = *(const float4*)&Asf[dd*ASTR + ty*4 + 64];
            float4 B0 = *(const float4*)&Bsf[dd*BN + tx*4];
            float4 B1 = *(const float4*)&Bsf[dd*BN + tx*4 + 64];
            float a[8] = {A0.x,A0.y,A0.z,A0.w,A1.x,A1.y,A1.z,A1.w};
            float b[8] = {B0.x,B0.y,B0.z,B0.w,B1.x,B1.y,B1.z,B1.w};
            #pragma unroll
            for (int i = 0; i < 8; ++i)
                #pragma unroll
                for (int j = 0; j < 8; ++j)
                    acc[i][j] = fmaf(a[i], b[j], acc[i][j]);
        }
    }

    int rl[8], cl[8];
    #pragma unroll
    for (int i = 0; i < 4; ++i) {
        rl[i] = ty*4 + i;  rl[i+4] = ty*4 + 64 + i;
        cl[i] = tx*4 + i;  cl[i+4] = tx*4 + 64 + i;
    }
    float xr[8], kc[8];
    #pragma unroll
    for (int i = 0; i < 8; ++i) { xr[i] = x2[bm0 + rl[i]]; kc[i] = k2[bn0 + cl[i]]; }

    #pragma unroll
    for (int i = 0; i < 8; ++i) {
        float vv[8];
        #pragma unroll
        for (int j = 0; j < 8; ++j)
            vv[j] = fmaxf((xr[i] - 2.f * acc[i][j]) + kc[j], 0.f);
        int gr = bm0 + rl[i];
        *(float4*)&out[(size_t)gr * K_ + bn0 + tx*4]      = make_float4(vv[0],vv[1],vv[2],vv[3]);
        *(float4*)&out[(size_t)gr * K_ + bn0 + tx*4 + 64] = make_float4(vv[4],vv[5],vv[6],vv[7]);
    }
}

__global__ __launch_bounds__(256) void rowscan(
    const float* __restrict__ out, const float* __restrict__ X,
    const float* __restrict__ Kmat, int* __restrict__ widx)
{
    const int row = blockIdx.x;
    const int t = threadIdx.x;
    const float* orow = out + (size_t)row * K_;

    float mn = 3.4e38f;
    for (int i = t; i < K_/4; i += 256) {
        float4 v = ((const float4*)orow)[i];
        mn = fminf(mn, fminf(fminf(v.x, v.y), fminf(v.z, v.w)));
    }
    __shared__ float smin[256];
    smin[t] = mn; __syncthreads();
    for (int off = 128; off > 0; off >>= 1) {
        if (t < off) smin[t] = fminf(smin[t], smin[t+off]);
        __syncthreads();
    }
    const float rowmin = smin[0];

    __shared__ int scnt;
    __shared__ int cand[MAXCAND];
    if (t == 0) scnt = 0;
    __syncthreads();
    const float thr = rowmin + EPS_CAND;
    for (int i = t; i < K_/4; i += 256) {
        float4 v = ((const float4*)orow)[i];
        float vv[4] = {v.x, v.y, v.z, v.w};
        #pragma unroll
        for (int j = 0; j < 4; ++j) {
            if (vv[j] <= thr) {
                int p = atomicAdd(&scnt, 1);
                if (p < MAXCAND) cand[p] = i*4 + j;
            }
        }
    }
    __syncthreads();
    const int cnt = min(scnt, MAXCAND);
    if (cnt == 1) {
        if (t == 0) widx[row] = cand[0];
        return;
    }

    const float* xrow = X + (size_t)row * D_;
    __shared__ double sred[256];
    double xs = 0.0;
    for (int d = t; d < D_; d += 256) {
        float xv = xrow[d];
        float sq = xv * xv;
        xs += (double)sq;
    }
    sred[t] = xs; __syncthreads();
    for (int off = 128; off > 0; off >>= 1) {
        if (t < off) sred[t] += sred[t+off];
        __syncthreads();
    }
    const float x2f = (float)sred[0];
    __syncthreads();

    __shared__ float cscore[MAXCAND];
    for (int c = 0; c < cnt; ++c) {
        const int k = cand[c];
        double dt = 0.0, kk = 0.0;
        for (int d = t; d < D_; d += 256) {
            float wv = Kmat[(size_t)d * K_ + k];
            float xv = xrow[d];
            dt += (double)xv * (double)wv;
            float w2 = wv * wv;
            kk += (double)w2;
        }
        sred[t] = dt; __syncthreads();
        for (int off = 128; off > 0; off >>= 1) {
            if (t < off) sred[t] += sred[t+off];
            __syncthreads();
        }
        const float dotf = (float)sred[0];
        __syncthreads();
        sred[t] = kk; __syncthreads();
        for (int off = 128; off > 0; off >>= 1) {
            if (t < off) sred[t] += sred[t+off];
            __syncthreads();
        }
        if (t == 0) {
            const float k2f = (float)sred[0];
            cscore[c] = fmaxf((x2f - 2.0f * dotf) + k2f, 0.0f);
        }
        __syncthreads();
    }
    if (t == 0) {
        float bv = cscore[0]; int bi = cand[0];
        for (int c = 1; c < cnt; ++c) {
            if (cscore[c] < bv || (cscore[c] == bv && cand[c] < bi)) {
                bv = cscore[c]; bi = cand[c];
            }
        }
        widx[row] = bi;
    }
}

__global__ void finalize(float* __restrict__ out, const int* __restrict__ widx,
                         const float* __restrict__ sigma) {
    size_t gid = (size_t)blockIdx.x * blockDim.x + threadIdx.x;
    int row = (int)(gid / (K_ / 4));
    int c4  = (int)(gid % (K_ / 4)) * 4;
    int w = widx[row];
    float wx = (float)(w >> 7), wy = (float)(w & 127);
    float sg = sigma[0];
    float ninv  = -0.5f / (sg * sg);
    float scale = 1.0f / (sg * sqrtf(2.0f * 3.14159265358979323846f));
    float4 v = *(float4*)&out[(size_t)row * K_ + c4];
    float* vp = (float*)&v;
    #pragma unroll
    for (int j = 0; j < 4; ++j) {
        int k = c4 + j;
        float gx = (float)(k >> 7), gy = (float)(k & 127);
        float dx = gx - wx, dy = gy - wy;
        float d2 = dx*dx + dy*dy;
        vp[j] = vp[j] * (__expf(ninv * d2) * scale);
    }
    *(float4*)&out[(size_t)row * K_ + c4] = v;
}

extern "C" void kernel_launch(void* const* d_in, const int* in_sizes, int n_in,
                              void* d_out, int out_size, void* d_ws, size_t ws_size,
                              hipStream_t stream) {
    const float* x     = (const float*)d_in[0];
    const float* kmat  = (const float*)d_in[1];
    const float* sigma = (const float*)d_in[2];
    float* out = (float*)d_out;

    const size_t BT_BYTES = (size_t)K_ * D_ * 2;   // 64 MB
    const size_t AH_BYTES = (size_t)B_ * D_ * 2;   // 16 MB
    // floats after Bt|Ah: k2[16384] x2[4096] pk2b[32*16384] pmin[4096*64]
    const size_t WS_NEED  = BT_BYTES + AH_BYTES +
        (size_t)(16384 + 4096 + 32*16384 + 4096*64) * 4;

    if (ws_size >= WS_NEED) {
        short* Bt   = (short*)d_ws;
        short* Ahp  = (short*)((char*)d_ws + BT_BYTES);
        float* k2   = (float*)((char*)d_ws + BT_BYTES + AH_BYTES);
        float* x2   = k2 + 16384;
        float* pk2b = x2 + 4096;
        float* pmin = pk2b + 32*16384;

        pack_a_x2 <<<B_, 256, 0, stream>>>(x, Ahp, x2);
        pack_bt_k2<<<dim3(K_/64, D_/64), 256, 0, stream>>>(kmat, Bt, pk2b);
        k2_reduce32<<<K_/256, 256, 0, stream>>>(pk2b, k2);
        gemm_8ph  <<<1024, 512, 0, stream>>>(Ahp, Bt, x2, k2, out, pmin);
        rowpost   <<<B_, 256, 0, stream>>>(out, x, kmat, pmin, sigma);
    } else {
        float* ws = (float*)d_ws;
        float* k2   = ws;
        float* x2   = ws + 16384;
        int*   widx = (int*)(ws + 20480);
        float* pk2  = ws + 24576;

        k2_partial<<<dim3(K_/256, 8), 256, 0, stream>>>(kmat, pk2);
        k2_reduce <<<K_/256, 256, 0, stream>>>(pk2, k2);
        x2_kernel <<<B_, 256, 0, stream>>>(x, x2);
        gemm_norms<<<dim3(K_/BN, B_/BM), 256, 0, stream>>>(x, kmat, x2, k2, out);
        rowscan   <<<B_, 256, 0, stream>>>(out, x, kmat, widx);
        finalize  <<<(size_t)B_ * (K_/4) / 256, 256, 0, stream>>>(out, widx, sigma);
    }
}

// Round 7
// 446.308 us; speedup vs baseline: 7.3772x; 1.2368x over previous
//
#include <hip/hip_runtime.h>
#include <math.h>

// Problem constants
#define B_    4096
#define D_    2048
#define K_    16384
#define SIDE  128

// f32-fallback GEMM tiling
#define BM 128
#define BN 128
#define BD 16
#define ASTR 132

// Argmin refinement
#define EPS_CAND 0.04f
#define MARGIN   0.015f
#define MAXCAND  64
#define RMAX     12

// 8-phase GEMM
#define NKT 32   // 2048 / 64

typedef __attribute__((ext_vector_type(8))) short bf16x8;
typedef __attribute__((ext_vector_type(4))) float f32x4;

__device__ __forceinline__ short bf16_rne(float f) {
    unsigned u = __float_as_uint(f);
    unsigned r = u + 0x7FFFu + ((u >> 16) & 1u);
    return (short)(r >> 16);
}

__device__ __forceinline__ void gload16(const void* g, void* l) {
    __builtin_amdgcn_global_load_lds(
        (const __attribute__((address_space(1))) unsigned int*)g,
        (__attribute__((address_space(3))) unsigned int*)l, 16, 0, 0);
}

// ---------------- pack x -> Ah (bf16) + x2 row sums, fused ----------------
__global__ __launch_bounds__(256) void pack_a_x2(const float* __restrict__ x,
                                                 short* __restrict__ Ah,
                                                 float* __restrict__ x2) {
    const int row = blockIdx.x;
    const int t = threadIdx.x;
    const size_t i = (size_t)row * 2048 + (size_t)t * 8;
    float4 v0 = *(const float4*)&x[i];
    float4 v1 = *(const float4*)&x[i + 4];
    short tmp[8] = { bf16_rne(v0.x), bf16_rne(v0.y), bf16_rne(v0.z), bf16_rne(v0.w),
                     bf16_rne(v1.x), bf16_rne(v1.y), bf16_rne(v1.z), bf16_rne(v1.w) };
    *(int4*)&Ah[i] = *(const int4*)tmp;
    float s = v0.x*v0.x + v0.y*v0.y + v0.z*v0.z + v0.w*v0.w
            + v1.x*v1.x + v1.y*v1.y + v1.z*v1.z + v1.w*v1.w;
    __shared__ float red[256];
    red[t] = s; __syncthreads();
    for (int off = 128; off > 0; off >>= 1) {
        if (t < off) red[t] += red[t + off];
        __syncthreads();
    }
    if (t == 0) x2[row] = red[0];
}

// ---------------- pack kernel -> Bt (bf16 transposed) + k2 partials, fused ----------------
__global__ __launch_bounds__(256) void pack_bt_k2(const float* __restrict__ kmat,
                                                  short* __restrict__ Bt,
                                                  float* __restrict__ pk2b) {
    __shared__ float tile[64][65];
    const int n0 = blockIdx.x * 64, d0 = blockIdx.y * 64;
    const int t = threadIdx.x;
    const int lr = t >> 4, lc4 = (t & 15) * 4;
    #pragma unroll
    for (int r = 0; r < 4; ++r) {
        float4 v = *(const float4*)&kmat[(size_t)(d0 + lr + r*16) * K_ + n0 + lc4];
        tile[lr + r*16][lc4 + 0] = v.x;
        tile[lr + r*16][lc4 + 1] = v.y;
        tile[lr + r*16][lc4 + 2] = v.z;
        tile[lr + r*16][lc4 + 3] = v.w;
    }
    __syncthreads();
    const int n = t >> 2, dc = (t & 3) * 16;
    short tmp[16];
    float s = 0.f;
    #pragma unroll
    for (int i = 0; i < 16; ++i) {
        float v = tile[dc + i][n];
        tmp[i] = bf16_rne(v);
        s = fmaf(v, v, s);
    }
    short* dst = &Bt[(size_t)(n0 + n) * 2048 + d0 + dc];
    *(int4*)dst       = *(const int4*)tmp;
    *(int4*)(dst + 8) = *(const int4*)(tmp + 8);
    s += __shfl_xor(s, 1);
    s += __shfl_xor(s, 2);
    if ((t & 3) == 0) pk2b[(size_t)(d0 >> 6) * K_ + n0 + n] = s;
}

__global__ void k2_reduce32(const float* __restrict__ pk2b, float* __restrict__ k2) {
    int k = blockIdx.x * 256 + threadIdx.x;
    float s = 0.f;
    #pragma unroll
    for (int j = 0; j < 32; ++j) s += pk2b[(size_t)j * K_ + k];
    k2[k] = s;
}

// ---------------- 8-phase 256x256 bf16 MFMA GEMM -> norms2 -> d_out + pmin ----------------
// pmin layout: [64 n-blocks][4096 rows]
__global__ __launch_bounds__(512, 2) void gemm_8ph(
    const short* __restrict__ Ah, const short* __restrict__ Bt,
    const float* __restrict__ x2, const float* __restrict__ k2,
    float* __restrict__ out, float* __restrict__ pmin)
{
    __shared__ short As[4 * 8192];
    __shared__ short Bs[4 * 8192];

    const int tid = threadIdx.x;
    const int lane = tid & 63;
    const int w = tid >> 6;
    const int wm = w >> 2, wn = w & 3;
    const int lrow = lane & 15, lkg = lane >> 4;

    // XCD-aware swizzle: 1024 blocks = 8 xcds x (8 bn-chunk x 16 bm)
    const int orig = blockIdx.x;
    const int xcd = orig & 7, seq = orig >> 3;
    const int bn0 = (xcd * 8 + (seq & 7)) * 256;
    const int bm0 = (seq >> 3) * 256;

    const int csw = ((tid & 3) ^ ((tid >> 3) & 3)) * 8;   // pre-swizzled source chunk
    const short* pA = Ah + (size_t)(bm0 + (tid >> 2)) * 2048 + csw;
    const short* pB = Bt + (size_t)(bn0 + (tid >> 2)) * 2048 + csw;
    const int ldsT = tid * 8;

    const int rsw = (lkg ^ ((lrow >> 1) & 3)) * 8;        // read-side swizzle
    const int aBase = (wm * 128 + lrow) * 32 + rsw;
    const int bBase = (wn * 64 + lrow) * 32 + rsw;

    f32x4 acc[8][4];
    #pragma unroll
    for (int i = 0; i < 8; ++i)
        #pragma unroll
        for (int j = 0; j < 4; ++j) acc[i][j] = (f32x4){0.f, 0.f, 0.f, 0.f};

#define STAGE(MATL, PTR, KS, T) do { \
    short* _l = (MATL) + ((((T) & 1) * 2 + (KS)) * 8192) + ldsT; \
    const short* _g = (PTR) + (size_t)(T) * 64 + (KS) * 32; \
    gload16(_g, _l); \
    gload16(_g + (size_t)128 * 2048, _l + 4096); \
} while (0)

#define PH_SYNC1 do { __builtin_amdgcn_sched_barrier(0); __builtin_amdgcn_s_barrier(); \
    asm volatile("s_waitcnt lgkmcnt(0)" ::: "memory"); __builtin_amdgcn_sched_barrier(0); \
    __builtin_amdgcn_s_setprio(1); } while (0)
#define PH_SYNC2 do { __builtin_amdgcn_s_setprio(0); __builtin_amdgcn_sched_barrier(0); \
    __builtin_amdgcn_s_barrier(); } while (0)

    STAGE(As, pA, 0, 0); STAGE(Bs, pB, 0, 0);
    STAGE(As, pA, 1, 0); STAGE(Bs, pB, 1, 0);
    STAGE(As, pA, 0, 1); STAGE(Bs, pB, 0, 1);
    asm volatile("s_waitcnt vmcnt(4)" ::: "memory");
    __builtin_amdgcn_s_barrier();

    for (int t = 0; t < NKT; ++t) {
        const int rg = (t & 1) * 2;
        const short* Ar0 = &As[rg * 8192];
        const short* Br0 = &Bs[rg * 8192];
        const short* Ar1 = Ar0 + 8192;
        const short* Br1 = Br0 + 8192;
        bf16x8 a[8], b0, b1, b2, b3;

        // ---- P1: ksub0, nh0 ----
        #pragma unroll
        for (int mf = 0; mf < 8; ++mf) a[mf] = *(const bf16x8*)&Ar0[aBase + mf * 512];
        b0 = *(const bf16x8*)&Br0[bBase];
        b1 = *(const bf16x8*)&Br0[bBase + 512];
        if (t + 1 < NKT) STAGE(As, pA, 1, t + 1);
        PH_SYNC1;
        #pragma unroll
        for (int mf = 0; mf < 8; ++mf) {
            acc[mf][0] = __builtin_amdgcn_mfma_f32_16x16x32_bf16(a[mf], b0, acc[mf][0], 0, 0, 0);
            acc[mf][1] = __builtin_amdgcn_mfma_f32_16x16x32_bf16(a[mf], b1, acc[mf][1], 0, 0, 0);
        }
        PH_SYNC2;

        // ---- P2: ksub0, nh1 ----
        b2 = *(const bf16x8*)&Br0[bBase + 1024];
        b3 = *(const bf16x8*)&Br0[bBase + 1536];
        if (t + 1 < NKT) STAGE(Bs, pB, 1, t + 1);
        PH_SYNC1;
        #pragma unroll
        for (int mf = 0; mf < 8; ++mf) {
            acc[mf][2] = __builtin_amdgcn_mfma_f32_16x16x32_bf16(a[mf], b2, acc[mf][2], 0, 0, 0);
            acc[mf][3] = __builtin_amdgcn_mfma_f32_16x16x32_bf16(a[mf], b3, acc[mf][3], 0, 0, 0);
        }
        PH_SYNC2;

        // ---- P3: ksub1, nh0 ----
        #pragma unroll
        for (int mf = 0; mf < 8; ++mf) a[mf] = *(const bf16x8*)&Ar1[aBase + mf * 512];
        b0 = *(const bf16x8*)&Br1[bBase];
        b1 = *(const bf16x8*)&Br1[bBase + 512];
        if (t + 2 < NKT) STAGE(As, pA, 0, t + 2);
        PH_SYNC1;
        #pragma unroll
        for (int mf = 0; mf < 8; ++mf) {
            acc[mf][0] = __builtin_amdgcn_mfma_f32_16x16x32_bf16(a[mf], b0, acc[mf][0], 0, 0, 0);
            acc[mf][1] = __builtin_amdgcn_mfma_f32_16x16x32_bf16(a[mf], b1, acc[mf][1], 0, 0, 0);
        }
        PH_SYNC2;

        // ---- P4: ksub1, nh1 ----
        b2 = *(const bf16x8*)&Br1[bBase + 1024];
        b3 = *(const bf16x8*)&Br1[bBase + 1536];
        if (t + 2 < NKT) STAGE(Bs, pB, 0, t + 2);
        PH_SYNC1;
        #pragma unroll
        for (int mf = 0; mf < 8; ++mf) {
            acc[mf][2] = __builtin_amdgcn_mfma_f32_16x16x32_bf16(a[mf], b2, acc[mf][2], 0, 0, 0);
            acc[mf][3] = __builtin_amdgcn_mfma_f32_16x16x32_bf16(a[mf], b3, acc[mf][3], 0, 0, 0);
        }
        __builtin_amdgcn_s_setprio(0);
        __builtin_amdgcn_sched_barrier(0);
        // last-2-iter drain: P3/P4 stop staging, so vmcnt(4) would leave this
        // tile's k1 (or next tile's) loads uncovered -> full drain instead.
        if (t + 2 < NKT) asm volatile("s_waitcnt vmcnt(4)" ::: "memory");
        else             asm volatile("s_waitcnt vmcnt(0)" ::: "memory");
        __builtin_amdgcn_s_barrier();
    }
#undef STAGE
#undef PH_SYNC1
#undef PH_SYNC2

    // ---- epilogue: norms2 scalar stores + register/shfl per-row block-min ----
    // C/D frag: col = lane&15, row = (lane>>4)*4 + j
    const int r0 = bm0 + wm * 128 + lkg * 4;
    const int c0 = bn0 + wn * 64 + lrow;
    float kc[4];
    #pragma unroll
    for (int nf = 0; nf < 4; ++nf) kc[nf] = k2[c0 + nf * 16];

    float* sm2 = (float*)As;   // [4 wn][256 rows] = 4 KB, reuse staging LDS
    __syncthreads();

    #pragma unroll
    for (int mf = 0; mf < 8; ++mf) {
        #pragma unroll
        for (int jj = 0; jj < 4; ++jj) {
            const int gr = r0 + mf * 16 + jj;
            const float xv = x2[gr];
            float* orow = out + (size_t)gr * K_ + c0;
            float v0 = fmaxf((xv - 2.f * acc[mf][0][jj]) + kc[0], 0.f);
            float v1 = fmaxf((xv - 2.f * acc[mf][1][jj]) + kc[1], 0.f);
            float v2 = fmaxf((xv - 2.f * acc[mf][2][jj]) + kc[2], 0.f);
            float v3 = fmaxf((xv - 2.f * acc[mf][3][jj]) + kc[3], 0.f);
            orow[0]  = v0;
            orow[16] = v1;
            orow[32] = v2;
            orow[48] = v3;
            float m = fminf(fminf(v0, v1), fminf(v2, v3));
            m = fminf(m, __shfl_xor(m, 1));
            m = fminf(m, __shfl_xor(m, 2));
            m = fminf(m, __shfl_xor(m, 4));
            m = fminf(m, __shfl_xor(m, 8));
            if (lrow == 0)
                sm2[wn * 256 + wm * 128 + mf * 16 + lkg * 4 + jj] = m;
        }
    }
    __syncthreads();
    if (tid < 256) {
        float m = fminf(fminf(sm2[tid], sm2[256 + tid]),
                        fminf(sm2[512 + tid], sm2[768 + tid]));
        pmin[(size_t)(bn0 >> 8) * 4096 + bm0 + tid] = m;
    }
}

// ---------------- fused rowmin/candidates/refine + patch-radial write ----------------
__global__ __launch_bounds__(256) void rowpost(
    float* __restrict__ out, const float* __restrict__ X,
    const float* __restrict__ Kmat, const float* __restrict__ pmin,
    const float* __restrict__ sigma)
{
    const int row = blockIdx.x;
    const int t = threadIdx.x;
    float* orow = out + (size_t)row * K_;

    __shared__ float sblk[64];
    __shared__ float sgmin;
    __shared__ int scnt, swidx, needRefine;
    __shared__ int cand[MAXCAND];
    __shared__ float cval[MAXCAND];
    __shared__ double sred[256];
    __shared__ float cscore[MAXCAND];
    __shared__ float patch[(2*RMAX+1)*(2*RMAX+1)];

    if (t < 64) sblk[t] = pmin[(size_t)t * 4096 + row];
    if (t == 0) scnt = 0;
    __syncthreads();
    if (t == 0) {
        float m = sblk[0];
        for (int i = 1; i < 64; ++i) m = fminf(m, sblk[i]);
        sgmin = m;
    }
    __syncthreads();
    const float thr = sgmin + EPS_CAND;

    // candidate collection: only blocks whose min can reach thr
    for (int b = 0; b < 64; ++b) {
        if (sblk[b] <= thr) {
            float v = orow[b * 256 + t];
            if (v <= thr) {
                int p = atomicAdd(&scnt, 1);
                if (p < MAXCAND) { cand[p] = b * 256 + t; cval[p] = v; }
            }
        }
    }
    __syncthreads();
    const int cnt = min(scnt, MAXCAND);

    if (cnt == 1) {
        if (t == 0) { swidx = cand[0]; needRefine = 0; }
        __syncthreads();
    } else {
        // stored-margin test: if stored best leads by > MARGIN, it is the gold winner
        if (t == 0) {
            float bv = cval[0]; int bi = cand[0];
            for (int c = 1; c < cnt; ++c)
                if (cval[c] < bv || (cval[c] == bv && cand[c] < bi)) { bv = cval[c]; bi = cand[c]; }
            float sv = 3.4e38f;
            for (int c = 0; c < cnt; ++c)
                if (cand[c] != bi) sv = fminf(sv, cval[c]);
            if (sv - bv > MARGIN) { swidx = bi; needRefine = 0; }
            else needRefine = 1;
        }
        __syncthreads();
        if (needRefine) {
            // gold emulation: each primitive exact-f64, then f32-rounded
            const float* xrow = X + (size_t)row * D_;
            double xs = 0.0;
            for (int d = t; d < D_; d += 256) {
                float xv = xrow[d];
                float sq = xv * xv;
                xs += (double)sq;
            }
            sred[t] = xs; __syncthreads();
            for (int off = 128; off > 0; off >>= 1) {
                if (t < off) sred[t] += sred[t + off];
                __syncthreads();
            }
            const float x2f = (float)sred[0];
            __syncthreads();

            for (int c = 0; c < cnt; ++c) {
                const int k = cand[c];
                double dt = 0.0, kk = 0.0;
                for (int d = t; d < D_; d += 256) {
                    float wv = Kmat[(size_t)d * K_ + k];
                    float xv = xrow[d];
                    dt += (double)xv * (double)wv;
                    float w2 = wv * wv;
                    kk += (double)w2;
                }
                sred[t] = dt; __syncthreads();
                for (int off = 128; off > 0; off >>= 1) {
                    if (t < off) sred[t] += sred[t + off];
                    __syncthreads();
                }
                const float dotf = (float)sred[0];
                __syncthreads();
                sred[t] = kk; __syncthreads();
                for (int off = 128; off > 0; off >>= 1) {
                    if (t < off) sred[t] += sred[t + off];
                    __syncthreads();
                }
                if (t == 0) {
                    const float k2f = (float)sred[0];
                    cscore[c] = fmaxf((x2f - 2.0f * dotf) + k2f, 0.0f);
                }
                __syncthreads();
            }
            if (t == 0) {
                float bv = cscore[0]; int bi = cand[0];
                for (int c = 1; c < cnt; ++c) {
                    if (cscore[c] < bv || (cscore[c] == bv && cand[c] < bi)) {
                        bv = cscore[c]; bi = cand[c];
                    }
                }
                swidx = bi;
            }
            __syncthreads();
        }
    }

    // ---- radial write: values outside radius R are < 0.5 -> write zeros, skip read ----
    const int wi = swidx;
    const int wx = wi >> 7, wy = wi & 127;
    const float sg = sigma[0];
    const float ninv  = -0.5f / (sg * sg);
    const float scale = 1.0f / (sg * sqrtf(2.0f * 3.14159265358979323846f));
    // drop bound: scale*exp(-R^2/(2 sg^2))*4096 <= 0.5
    float larg = 8192.0f * scale;
    int R = (larg <= 1.0f) ? 0
          : (int)ceilf(sg * sqrtf(2.0f * logf(larg)));

    if (R <= RMAX) {
        const int W = 2 * R + 1;
        for (int p = t; p < W * W; p += 256) {
            int dx = p / W - R, dy = p % W - R;
            int gx = wx + dx, gy = wy + dy;
            if ((unsigned)gx < 128u && (unsigned)gy < 128u)
                patch[p] = orow[gx * 128 + gy];
        }
        __syncthreads();
        for (int i = t; i < K_ / 4; i += 256) {
            const int k0 = i * 4;
            const int gx = k0 >> 7;
            const int dx = gx - wx;
            float4 v = make_float4(0.f, 0.f, 0.f, 0.f);
            float* vp = (float*)&v;
            if (dx >= -R && dx <= R) {
                #pragma unroll
                for (int j = 0; j < 4; ++j) {
                    int gy = (k0 & 127) + j;
                    int dy = gy - wy;
                    if (dy >= -R && dy <= R) {
                        float d2 = (float)(dx * dx + dy * dy);
                        vp[j] = patch[(dx + R) * W + (dy + R)] * (scale * __expf(ninv * d2));
                    }
                }
            }
            *(float4*)&orow[k0] = v;
        }
    } else {
        // general-sigma fallback: full read-modify-write
        for (int i = t; i < K_ / 4; i += 256) {
            float4 v = ((const float4*)orow)[i];
            float* vp = (float*)&v;
            #pragma unroll
            for (int j = 0; j < 4; ++j) {
                int k = i * 4 + j;
                float gx = (float)(k >> 7), gy = (float)(k & 127);
                float dx = gx - (float)wx, dy = gy - (float)wy;
                float d2 = dx * dx + dy * dy;
                vp[j] = vp[j] * (__expf(ninv * d2) * scale);
            }
            ((float4*)orow)[i] = v;
        }
    }
}

// ================= f32 fallback path (unchanged round-3 kernels) =================
__global__ void k2_partial(const float* __restrict__ kmat, float* __restrict__ pk2) {
    int k  = blockIdx.x * 256 + threadIdx.x;
    int d0 = blockIdx.y * 256;
    float s = 0.f;
    #pragma unroll 8
    for (int d = 0; d < 256; ++d) {
        float v = kmat[(size_t)(d0 + d) * K_ + k];
        s = fmaf(v, v, s);
    }
    pk2[(size_t)blockIdx.y * K_ + k] = s;
}

__global__ void k2_reduce(const float* __restrict__ pk2, float* __restrict__ k2) {
    int k = blockIdx.x * 256 + threadIdx.x;
    float s = 0.f;
    #pragma unroll
    for (int j = 0; j < 8; ++j) s += pk2[(size_t)j * K_ + k];
    k2[k] = s;
}

__global__ void x2_kernel(const float* __restrict__ x, float* __restrict__ x2) {
    int row = blockIdx.x;
    const float* xr = x + (size_t)row * D_;
    int t = threadIdx.x;
    float4 v0 = ((const float4*)xr)[t];
    float4 v1 = ((const float4*)xr)[t + 256];
    float s = v0.x*v0.x + v0.y*v0.y + v0.z*v0.z + v0.w*v0.w
            + v1.x*v1.x + v1.y*v1.y + v1.z*v1.z + v1.w*v1.w;
    __shared__ float red[256];
    red[t] = s; __syncthreads();
    for (int off = 128; off > 0; off >>= 1) {
        if (t < off) red[t] += red[t + off];
        __syncthreads();
    }
    if (t == 0) x2[row] = red[0];
}

__global__ __launch_bounds__(256) void gemm_norms(
    const float* __restrict__ X, const float* __restrict__ Kmat,
    const float* __restrict__ x2, const float* __restrict__ k2,
    float* __restrict__ out)
{
    __shared__ float Asf[BD * ASTR];
    __shared__ float Bsf[BD * BN];

    const int tid = threadIdx.x;
    const int tx = tid & 15, ty = tid >> 4;
    const int bn0 = blockIdx.x * BN;
    const int bm0 = blockIdx.y * BM;

    float acc[8][8];
    #pragma unroll
    for (int i = 0; i < 8; ++i)
        #pragma unroll
        for (int j = 0; j < 8; ++j) acc[i][j] = 0.f;

    const int lm = tid >> 2;
    const int ld = (tid & 3) << 2;
    const int bd = tid >> 5;
    const int bk = (tid & 31) << 2;

    const float* Xp = X    + (size_t)(bm0 + lm) * D_ + ld;
    const float* Kp = Kmat + (size_t)bd * K_ + bn0 + bk;

    float4 a0 = *(const float4*)(Xp);
    float4 a1 = *(const float4*)(Xp + (size_t)64 * D_);
    float4 b0 = *(const float4*)(Kp);
    float4 b1 = *(const float4*)(Kp + (size_t)8 * K_);

    const int NT = D_ / BD;
    for (int kt = 0; kt < NT; ++kt) {
        __syncthreads();
        Asf[(ld+0)*ASTR + lm]      = a0.x;
        Asf[(ld+1)*ASTR + lm]      = a0.y;
        Asf[(ld+2)*ASTR + lm]      = a0.z;
        Asf[(ld+3)*ASTR + lm]      = a0.w;
        Asf[(ld+0)*ASTR + lm + 64] = a1.x;
        Asf[(ld+1)*ASTR + lm + 64] = a1.y;
        Asf[(ld+2)*ASTR + lm + 64] = a1.z;
        Asf[(ld+3)*ASTR + lm + 64] = a1.w;
        *(float4*)&Bsf[bd*BN + bk]     = b0;
        *(float4*)&Bsf[(bd+8)*BN + bk] = b1;
        __syncthreads();

        if (kt + 1 < NT) {
            const float* Xn = Xp + (kt + 1) * BD;
            const float* Kn = Kp + (size_t)(kt + 1) * BD * K_;
            a0 = *(const float4*)(Xn);
            a1 = *(const float4*)(Xn + (size_t)64 * D_);
            b0 = *(const float4*)(Kn);
            b1 = *(const float4*)(Kn + (size_t)8 * K_);
        }

        #pragma unroll
        for (int dd = 0; dd < BD; ++dd) {
            float4 A0 = *(const float4*)&Asf[dd*ASTR + ty*4];
            float4 A1 = *(const float4*)&Asf[dd*ASTR + ty*4 + 64];
            float4 B0 = *(const float4*)&Bsf[dd*BN + tx*4];
            float4 B1 = *(const float4*)&Bsf[dd*BN + tx*4 + 64];
            float a[8] = {A0.x,A0.y,A0.z,A0.w,A1.x,A1.y,A1.z,A1.w};
            float b[8] = {B0.x,B0.y,B0.z,B0.w,B1.x,B1.y,B1.z,B1.w};
            #pragma unroll
            for (int i = 0; i < 8; ++i)
                #pragma unroll
                for (int j = 0; j < 8; ++j)
                    acc[i][j] = fmaf(a[i], b[j], acc[i][j]);
        }
    }

    int rl[8], cl[8];
    #pragma unroll
    for (int i = 0; i < 4; ++i) {
        rl[i] = ty*4 + i;  rl[i+4] = ty*4 + 64 + i;
        cl[i] = tx*4 + i;  cl[i+4] = tx*4 + 64 + i;
    }
    float xr[8], kc[8];
    #pragma unroll
    for (int i = 0; i < 8; ++i) { xr[i] = x2[bm0 + rl[i]]; kc[i] = k2[bn0 + cl[i]]; }

    #pragma unroll
    for (int i = 0; i < 8; ++i) {
        float vv[8];
        #pragma unroll
        for (int j = 0; j < 8; ++j)
            vv[j] = fmaxf((xr[i] - 2.f * acc[i][j]) + kc[j], 0.f);
        int gr = bm0 + rl[i];
        *(float4*)&out[(size_t)gr * K_ + bn0 + tx*4]      = make_float4(vv[0],vv[1],vv[2],vv[3]);
        *(float4*)&out[(size_t)gr * K_ + bn0 + tx*4 + 64] = make_float4(vv[4],vv[5],vv[6],vv[7]);
    }
}

__global__ __launch_bounds__(256) void rowscan(
    const float* __restrict__ out, const float* __restrict__ X,
    const float* __restrict__ Kmat, int* __restrict__ widx)
{
    const int row = blockIdx.x;
    const int t = threadIdx.x;
    const float* orow = out + (size_t)row * K_;

    float mn = 3.4e38f;
    for (int i = t; i < K_/4; i += 256) {
        float4 v = ((const float4*)orow)[i];
        mn = fminf(mn, fminf(fminf(v.x, v.y), fminf(v.z, v.w)));
    }
    __shared__ float smin[256];
    smin[t] = mn; __syncthreads();
    for (int off = 128; off > 0; off >>= 1) {
        if (t < off) smin[t] = fminf(smin[t], smin[t+off]);
        __syncthreads();
    }
    const float rowmin = smin[0];

    __shared__ int scnt;
    __shared__ int cand[MAXCAND];
    if (t == 0) scnt = 0;
    __syncthreads();
    const float thr = rowmin + EPS_CAND;
    for (int i = t; i < K_/4; i += 256) {
        float4 v = ((const float4*)orow)[i];
        float vv[4] = {v.x, v.y, v.z, v.w};
        #pragma unroll
        for (int j = 0; j < 4; ++j) {
            if (vv[j] <= thr) {
                int p = atomicAdd(&scnt, 1);
                if (p < MAXCAND) cand[p] = i*4 + j;
            }
        }
    }
    __syncthreads();
    const int cnt = min(scnt, MAXCAND);
    if (cnt == 1) {
        if (t == 0) widx[row] = cand[0];
        return;
    }

    const float* xrow = X + (size_t)row * D_;
    __shared__ double sred[256];
    double xs = 0.0;
    for (int d = t; d < D_; d += 256) {
        float xv = xrow[d];
        float sq = xv * xv;
        xs += (double)sq;
    }
    sred[t] = xs; __syncthreads();
    for (int off = 128; off > 0; off >>= 1) {
        if (t < off) sred[t] += sred[t+off];
        __syncthreads();
    }
    const float x2f = (float)sred[0];
    __syncthreads();

    __shared__ float cscore[MAXCAND];
    for (int c = 0; c < cnt; ++c) {
        const int k = cand[c];
        double dt = 0.0, kk = 0.0;
        for (int d = t; d < D_; d += 256) {
            float wv = Kmat[(size_t)d * K_ + k];
            float xv = xrow[d];
            dt += (double)xv * (double)wv;
            float w2 = wv * wv;
            kk += (double)w2;
        }
        sred[t] = dt; __syncthreads();
        for (int off = 128; off > 0; off >>= 1) {
            if (t < off) sred[t] += sred[t+off];
            __syncthreads();
        }
        const float dotf = (float)sred[0];
        __syncthreads();
        sred[t] = kk; __syncthreads();
        for (int off = 128; off > 0; off >>= 1) {
            if (t < off) sred[t] += sred[t+off];
            __syncthreads();
        }
        if (t == 0) {
            const float k2f = (float)sred[0];
            cscore[c] = fmaxf((x2f - 2.0f * dotf) + k2f, 0.0f);
        }
        __syncthreads();
    }
    if (t == 0) {
        float bv = cscore[0]; int bi = cand[0];
        for (int c = 1; c < cnt; ++c) {
            if (cscore[c] < bv || (cscore[c] == bv && cand[c] < bi)) {
                bv = cscore[c]; bi = cand[c];
            }
        }
        widx[row] = bi;
    }
}

__global__ void finalize(float* __restrict__ out, const int* __restrict__ widx,
                         const float* __restrict__ sigma) {
    size_t gid = (size_t)blockIdx.x * blockDim.x + threadIdx.x;
    int row = (int)(gid / (K_ / 4));
    int c4  = (int)(gid % (K_ / 4)) * 4;
    int w = widx[row];
    float wx = (float)(w >> 7), wy = (float)(w & 127);
    float sg = sigma[0];
    float ninv  = -0.5f / (sg * sg);
    float scale = 1.0f / (sg * sqrtf(2.0f * 3.14159265358979323846f));
    float4 v = *(float4*)&out[(size_t)row * K_ + c4];
    float* vp = (float*)&v;
    #pragma unroll
    for (int j = 0; j < 4; ++j) {
        int k = c4 + j;
        float gx = (float)(k >> 7), gy = (float)(k & 127);
        float dx = gx - wx, dy = gy - wy;
        float d2 = dx*dx + dy*dy;
        vp[j] = vp[j] * (__expf(ninv * d2) * scale);
    }
    *(float4*)&out[(size_t)row * K_ + c4] = v;
}

extern "C" void kernel_launch(void* const* d_in, const int* in_sizes, int n_in,
                              void* d_out, int out_size, void* d_ws, size_t ws_size,
                              hipStream_t stream) {
    const float* x     = (const float*)d_in[0];
    const float* kmat  = (const float*)d_in[1];
    const float* sigma = (const float*)d_in[2];
    float* out = (float*)d_out;

    const size_t BT_BYTES = (size_t)K_ * D_ * 2;   // 64 MB
    const size_t AH_BYTES = (size_t)B_ * D_ * 2;   // 16 MB
    // floats after Bt|Ah: k2[16384] x2[4096] pk2b[32*16384] pmin[64*4096]
    const size_t WS_NEED  = BT_BYTES + AH_BYTES +
        (size_t)(16384 + 4096 + 32*16384 + 64*4096) * 4;

    if (ws_size >= WS_NEED) {
        short* Bt   = (short*)d_ws;
        short* Ahp  = (short*)((char*)d_ws + BT_BYTES);
        float* k2   = (float*)((char*)d_ws + BT_BYTES + AH_BYTES);
        float* x2   = k2 + 16384;
        float* pk2b = x2 + 4096;
        float* pmin = pk2b + 32*16384;

        pack_a_x2 <<<B_, 256, 0, stream>>>(x, Ahp, x2);
        pack_bt_k2<<<dim3(K_/64, D_/64), 256, 0, stream>>>(kmat, Bt, pk2b);
        k2_reduce32<<<K_/256, 256, 0, stream>>>(pk2b, k2);
        gemm_8ph  <<<1024, 512, 0, stream>>>(Ahp, Bt, x2, k2, out, pmin);
        rowpost   <<<B_, 256, 0, stream>>>(out, x, kmat, pmin, sigma);
    } else {
        float* ws = (float*)d_ws;
        float* k2   = ws;
        float* x2   = ws + 16384;
        int*   widx = (int*)(ws + 20480);
        float* pk2  = ws + 24576;

        k2_partial<<<dim3(K_/256, 8), 256, 0, stream>>>(kmat, pk2);
        k2_reduce <<<K_/256, 256, 0, stream>>>(pk2, k2);
        x2_kernel <<<B_, 256, 0, stream>>>(x, x2);
        gemm_norms<<<dim3(K_/BN, B_/BM), 256, 0, stream>>>(x, kmat, x2, k2, out);
        rowscan   <<<B_, 256, 0, stream>>>(out, x, kmat, widx);
        finalize  <<<(size_t)B_ * (K_/4) / 256, 256, 0, stream>>>(out, widx, sigma);
    }
}

// Round 8
// 436.208 us; speedup vs baseline: 7.5480x; 1.0232x over previous
//
#include <hip/hip_runtime.h>
#include <math.h>

// Problem constants
#define B_    4096
#define D_    2048
#define K_    16384
#define SIDE  128

// f32-fallback GEMM tiling
#define BM 128
#define BN 128
#define BD 16
#define ASTR 132

// Argmin refinement
#define EPS_CAND 0.04f
#define MARGIN   0.015f
#define MAXCAND  64
#define RMAX     12

// GEMM
#define NKT 32   // 2048 / 64

typedef __attribute__((ext_vector_type(8))) short bf16x8;
typedef __attribute__((ext_vector_type(4))) float f32x4;

__device__ __forceinline__ short bf16_rne(float f) {
    unsigned u = __float_as_uint(f);
    unsigned r = u + 0x7FFFu + ((u >> 16) & 1u);
    return (short)(r >> 16);
}

__device__ __forceinline__ void gload16(const void* g, void* l) {
    __builtin_amdgcn_global_load_lds(
        (const __attribute__((address_space(1))) unsigned int*)g,
        (__attribute__((address_space(3))) unsigned int*)l, 16, 0, 0);
}

// ---------------- pack x -> Ah (bf16) + x2 row sums, fused ----------------
__global__ __launch_bounds__(256) void pack_a_x2(const float* __restrict__ x,
                                                 short* __restrict__ Ah,
                                                 float* __restrict__ x2) {
    const int row = blockIdx.x;
    const int t = threadIdx.x;
    const size_t i = (size_t)row * 2048 + (size_t)t * 8;
    float4 v0 = *(const float4*)&x[i];
    float4 v1 = *(const float4*)&x[i + 4];
    short tmp[8] = { bf16_rne(v0.x), bf16_rne(v0.y), bf16_rne(v0.z), bf16_rne(v0.w),
                     bf16_rne(v1.x), bf16_rne(v1.y), bf16_rne(v1.z), bf16_rne(v1.w) };
    *(int4*)&Ah[i] = *(const int4*)tmp;
    float s = v0.x*v0.x + v0.y*v0.y + v0.z*v0.z + v0.w*v0.w
            + v1.x*v1.x + v1.y*v1.y + v1.z*v1.z + v1.w*v1.w;
    __shared__ float red[256];
    red[t] = s; __syncthreads();
    for (int off = 128; off > 0; off >>= 1) {
        if (t < off) red[t] += red[t + off];
        __syncthreads();
    }
    if (t == 0) x2[row] = red[0];
}

// ---------------- pack kernel -> Bt (bf16 transposed) + k2 partials, fused ----------------
__global__ __launch_bounds__(256) void pack_bt_k2(const float* __restrict__ kmat,
                                                  short* __restrict__ Bt,
                                                  float* __restrict__ pk2b) {
    __shared__ float tile[64][65];
    const int n0 = blockIdx.x * 64, d0 = blockIdx.y * 64;
    const int t = threadIdx.x;
    const int lr = t >> 4, lc4 = (t & 15) * 4;
    #pragma unroll
    for (int r = 0; r < 4; ++r) {
        float4 v = *(const float4*)&kmat[(size_t)(d0 + lr + r*16) * K_ + n0 + lc4];
        tile[lr + r*16][lc4 + 0] = v.x;
        tile[lr + r*16][lc4 + 1] = v.y;
        tile[lr + r*16][lc4 + 2] = v.z;
        tile[lr + r*16][lc4 + 3] = v.w;
    }
    __syncthreads();
    const int n = t >> 2, dc = (t & 3) * 16;
    short tmp[16];
    float s = 0.f;
    #pragma unroll
    for (int i = 0; i < 16; ++i) {
        float v = tile[dc + i][n];
        tmp[i] = bf16_rne(v);
        s = fmaf(v, v, s);
    }
    short* dst = &Bt[(size_t)(n0 + n) * 2048 + d0 + dc];
    *(int4*)dst       = *(const int4*)tmp;
    *(int4*)(dst + 8) = *(const int4*)(tmp + 8);
    s += __shfl_xor(s, 1);
    s += __shfl_xor(s, 2);
    if ((t & 3) == 0) pk2b[(size_t)(d0 >> 6) * K_ + n0 + n] = s;
}

__global__ void k2_reduce32(const float* __restrict__ pk2b, float* __restrict__ k2) {
    int k = blockIdx.x * 256 + threadIdx.x;
    float s = 0.f;
    #pragma unroll
    for (int j = 0; j < 32; ++j) s += pk2b[(size_t)j * K_ + k];
    k2[k] = s;
}

// ---------------- pipelined 256x256 bf16 MFMA GEMM -> norms2 -> d_out + pmin ----------------
// One barrier per K-tile; ds_reads (ksub0 | ksub1) + next-tile staging issued up
// front, compiler-counted lgkmcnt overlaps ksub1 reads + staging with MFMA ksub0.
// pmin layout: [64 n-blocks][4096 rows]
__global__ __launch_bounds__(512, 2) void gemm_8ph(
    const short* __restrict__ Ah, const short* __restrict__ Bt,
    const float* __restrict__ x2, const float* __restrict__ k2,
    float* __restrict__ out, float* __restrict__ pmin)
{
    __shared__ short As[4 * 8192];
    __shared__ short Bs[4 * 8192];

    const int tid = threadIdx.x;
    const int lane = tid & 63;
    const int w = tid >> 6;
    const int wm = w >> 2, wn = w & 3;
    const int lrow = lane & 15, lkg = lane >> 4;

    // XCD-aware swizzle: 1024 blocks = 8 xcds x (8 bn-chunk x 16 bm)
    const int orig = blockIdx.x;
    const int xcd = orig & 7, seq = orig >> 3;
    const int bn0 = (xcd * 8 + (seq & 7)) * 256;
    const int bm0 = (seq >> 3) * 256;

    const int csw = ((tid & 3) ^ ((tid >> 3) & 3)) * 8;   // pre-swizzled source chunk
    const short* pA = Ah + (size_t)(bm0 + (tid >> 2)) * 2048 + csw;
    const short* pB = Bt + (size_t)(bn0 + (tid >> 2)) * 2048 + csw;
    const int ldsT = tid * 8;

    const int rsw = (lkg ^ ((lrow >> 1) & 3)) * 8;        // read-side swizzle
    const int aBase = (wm * 128 + lrow) * 32 + rsw;
    const int bBase = (wn * 64 + lrow) * 32 + rsw;

    f32x4 acc[8][4];
    #pragma unroll
    for (int i = 0; i < 8; ++i)
        #pragma unroll
        for (int j = 0; j < 4; ++j) acc[i][j] = (f32x4){0.f, 0.f, 0.f, 0.f};

#define STAGE(MATL, PTR, KS, T) do { \
    short* _l = (MATL) + ((((T) & 1) * 2 + (KS)) * 8192) + ldsT; \
    const short* _g = (PTR) + (size_t)(T) * 64 + (KS) * 32; \
    gload16(_g, _l); \
    gload16(_g + (size_t)128 * 2048, _l + 4096); \
} while (0)

    // prologue: stage tile 0 (both ksub halves of A and B), drain, barrier
    STAGE(As, pA, 0, 0); STAGE(As, pA, 1, 0);
    STAGE(Bs, pB, 0, 0); STAGE(Bs, pB, 1, 0);
    asm volatile("s_waitcnt vmcnt(0)" ::: "memory");
    __builtin_amdgcn_s_barrier();

    for (int t = 0; t < NKT; ++t) {
        const int rg = (t & 1) * 2;
        const short* Ar0 = &As[rg * 8192];
        const short* Br0 = &Bs[rg * 8192];
        const short* Ar1 = Ar0 + 8192;
        const short* Br1 = Br0 + 8192;
        bf16x8 a0[8], b0[4], a1[8], b1[4];

        // group 0 reads (ksub0)
        #pragma unroll
        for (int mf = 0; mf < 8; ++mf) a0[mf] = *(const bf16x8*)&Ar0[aBase + mf * 512];
        #pragma unroll
        for (int nf = 0; nf < 4; ++nf) b0[nf] = *(const bf16x8*)&Br0[bBase + nf * 512];
        __builtin_amdgcn_sched_barrier(0);
        // group 1 reads (ksub1) + next-tile staging — overlap MFMA ksub0
        #pragma unroll
        for (int mf = 0; mf < 8; ++mf) a1[mf] = *(const bf16x8*)&Ar1[aBase + mf * 512];
        #pragma unroll
        for (int nf = 0; nf < 4; ++nf) b1[nf] = *(const bf16x8*)&Br1[bBase + nf * 512];
        if (t + 1 < NKT) {
            STAGE(As, pA, 0, t + 1); STAGE(As, pA, 1, t + 1);
            STAGE(Bs, pB, 0, t + 1); STAGE(Bs, pB, 1, t + 1);
        }
        __builtin_amdgcn_sched_barrier(0);

        __builtin_amdgcn_s_setprio(1);
        #pragma unroll
        for (int mf = 0; mf < 8; ++mf) {
            acc[mf][0] = __builtin_amdgcn_mfma_f32_16x16x32_bf16(a0[mf], b0[0], acc[mf][0], 0, 0, 0);
            acc[mf][1] = __builtin_amdgcn_mfma_f32_16x16x32_bf16(a0[mf], b0[1], acc[mf][1], 0, 0, 0);
            acc[mf][2] = __builtin_amdgcn_mfma_f32_16x16x32_bf16(a0[mf], b0[2], acc[mf][2], 0, 0, 0);
            acc[mf][3] = __builtin_amdgcn_mfma_f32_16x16x32_bf16(a0[mf], b0[3], acc[mf][3], 0, 0, 0);
        }
        __builtin_amdgcn_sched_barrier(0);
        #pragma unroll
        for (int mf = 0; mf < 8; ++mf) {
            acc[mf][0] = __builtin_amdgcn_mfma_f32_16x16x32_bf16(a1[mf], b1[0], acc[mf][0], 0, 0, 0);
            acc[mf][1] = __builtin_amdgcn_mfma_f32_16x16x32_bf16(a1[mf], b1[1], acc[mf][1], 0, 0, 0);
            acc[mf][2] = __builtin_amdgcn_mfma_f32_16x16x32_bf16(a1[mf], b1[2], acc[mf][2], 0, 0, 0);
            acc[mf][3] = __builtin_amdgcn_mfma_f32_16x16x32_bf16(a1[mf], b1[3], acc[mf][3], 0, 0, 0);
        }
        __builtin_amdgcn_s_setprio(0);
        __builtin_amdgcn_sched_barrier(0);
        asm volatile("s_waitcnt vmcnt(0)" ::: "memory");
        __builtin_amdgcn_s_barrier();
    }
#undef STAGE

    // ---- epilogue: norms2 scalar stores + register/shfl per-row block-min ----
    // C/D frag: col = lane&15, row = (lane>>4)*4 + j
    const int r0 = bm0 + wm * 128 + lkg * 4;
    const int c0 = bn0 + wn * 64 + lrow;
    float kc[4];
    #pragma unroll
    for (int nf = 0; nf < 4; ++nf) kc[nf] = k2[c0 + nf * 16];

    float* sm2 = (float*)As;   // [4 wn][256 rows] = 4 KB, reuse staging LDS
    __syncthreads();

    #pragma unroll
    for (int mf = 0; mf < 8; ++mf) {
        #pragma unroll
        for (int jj = 0; jj < 4; ++jj) {
            const int gr = r0 + mf * 16 + jj;
            const float xv = x2[gr];
            float* orow = out + (size_t)gr * K_ + c0;
            float v0 = fmaxf((xv - 2.f * acc[mf][0][jj]) + kc[0], 0.f);
            float v1 = fmaxf((xv - 2.f * acc[mf][1][jj]) + kc[1], 0.f);
            float v2 = fmaxf((xv - 2.f * acc[mf][2][jj]) + kc[2], 0.f);
            float v3 = fmaxf((xv - 2.f * acc[mf][3][jj]) + kc[3], 0.f);
            orow[0]  = v0;
            orow[16] = v1;
            orow[32] = v2;
            orow[48] = v3;
            float m = fminf(fminf(v0, v1), fminf(v2, v3));
            m = fminf(m, __shfl_xor(m, 1));
            m = fminf(m, __shfl_xor(m, 2));
            m = fminf(m, __shfl_xor(m, 4));
            m = fminf(m, __shfl_xor(m, 8));
            if (lrow == 0)
                sm2[wn * 256 + wm * 128 + mf * 16 + lkg * 4 + jj] = m;
        }
    }
    __syncthreads();
    if (tid < 256) {
        float m = fminf(fminf(sm2[tid], sm2[256 + tid]),
                        fminf(sm2[512 + tid], sm2[768 + tid]));
        pmin[(size_t)(bn0 >> 8) * 4096 + bm0 + tid] = m;
    }
}

// ---------------- fused rowmin/candidates/refine + patch-radial write ----------------
__global__ __launch_bounds__(256) void rowpost(
    float* __restrict__ out, const float* __restrict__ X,
    const float* __restrict__ Kmat, const float* __restrict__ pmin,
    const float* __restrict__ sigma)
{
    const int row = blockIdx.x;
    const int t = threadIdx.x;
    float* orow = out + (size_t)row * K_;

    __shared__ float sblk[64];
    __shared__ float sgmin;
    __shared__ int scnt, swidx, needRefine;
    __shared__ int cand[MAXCAND];
    __shared__ float cval[MAXCAND];
    __shared__ double sred[256];
    __shared__ float cscore[MAXCAND];
    __shared__ float patch[(2*RMAX+1)*(2*RMAX+1)];

    if (t < 64) sblk[t] = pmin[(size_t)t * 4096 + row];
    if (t == 0) scnt = 0;
    __syncthreads();
    if (t == 0) {
        float m = sblk[0];
        for (int i = 1; i < 64; ++i) m = fminf(m, sblk[i]);
        sgmin = m;
    }
    __syncthreads();
    const float thr = sgmin + EPS_CAND;

    // candidate collection: only blocks whose min can reach thr
    for (int b = 0; b < 64; ++b) {
        if (sblk[b] <= thr) {
            float v = orow[b * 256 + t];
            if (v <= thr) {
                int p = atomicAdd(&scnt, 1);
                if (p < MAXCAND) { cand[p] = b * 256 + t; cval[p] = v; }
            }
        }
    }
    __syncthreads();
    const int cnt = min(scnt, MAXCAND);

    if (cnt == 1) {
        if (t == 0) { swidx = cand[0]; needRefine = 0; }
        __syncthreads();
    } else {
        // stored-margin test: if stored best leads by > MARGIN, it is the gold winner
        if (t == 0) {
            float bv = cval[0]; int bi = cand[0];
            for (int c = 1; c < cnt; ++c)
                if (cval[c] < bv || (cval[c] == bv && cand[c] < bi)) { bv = cval[c]; bi = cand[c]; }
            float sv = 3.4e38f;
            for (int c = 0; c < cnt; ++c)
                if (cand[c] != bi) sv = fminf(sv, cval[c]);
            if (sv - bv > MARGIN) { swidx = bi; needRefine = 0; }
            else needRefine = 1;
        }
        __syncthreads();
        if (needRefine) {
            // gold emulation: each primitive exact-f64, then f32-rounded
            const float* xrow = X + (size_t)row * D_;
            double xs = 0.0;
            for (int d = t; d < D_; d += 256) {
                float xv = xrow[d];
                float sq = xv * xv;
                xs += (double)sq;
            }
            sred[t] = xs; __syncthreads();
            for (int off = 128; off > 0; off >>= 1) {
                if (t < off) sred[t] += sred[t + off];
                __syncthreads();
            }
            const float x2f = (float)sred[0];
            __syncthreads();

            for (int c = 0; c < cnt; ++c) {
                const int k = cand[c];
                double dt = 0.0, kk = 0.0;
                for (int d = t; d < D_; d += 256) {
                    float wv = Kmat[(size_t)d * K_ + k];
                    float xv = xrow[d];
                    dt += (double)xv * (double)wv;
                    float w2 = wv * wv;
                    kk += (double)w2;
                }
                sred[t] = dt; __syncthreads();
                for (int off = 128; off > 0; off >>= 1) {
                    if (t < off) sred[t] += sred[t + off];
                    __syncthreads();
                }
                const float dotf = (float)sred[0];
                __syncthreads();
                sred[t] = kk; __syncthreads();
                for (int off = 128; off > 0; off >>= 1) {
                    if (t < off) sred[t] += sred[t + off];
                    __syncthreads();
                }
                if (t == 0) {
                    const float k2f = (float)sred[0];
                    cscore[c] = fmaxf((x2f - 2.0f * dotf) + k2f, 0.0f);
                }
                __syncthreads();
            }
            if (t == 0) {
                float bv = cscore[0]; int bi = cand[0];
                for (int c = 1; c < cnt; ++c) {
                    if (cscore[c] < bv || (cscore[c] == bv && cand[c] < bi)) {
                        bv = cscore[c]; bi = cand[c];
                    }
                }
                swidx = bi;
            }
            __syncthreads();
        }
    }

    // ---- radial write: values outside radius R are < 0.5 -> write zeros, skip read ----
    const int wi = swidx;
    const int wx = wi >> 7, wy = wi & 127;
    const float sg = sigma[0];
    const float ninv  = -0.5f / (sg * sg);
    const float scale = 1.0f / (sg * sqrtf(2.0f * 3.14159265358979323846f));
    // drop bound: scale*exp(-R^2/(2 sg^2))*4096 <= 0.5
    float larg = 8192.0f * scale;
    int R = (larg <= 1.0f) ? 0
          : (int)ceilf(sg * sqrtf(2.0f * logf(larg)));

    if (R <= RMAX) {
        const int W = 2 * R + 1;
        for (int p = t; p < W * W; p += 256) {
            int dx = p / W - R, dy = p % W - R;
            int gx = wx + dx, gy = wy + dy;
            if ((unsigned)gx < 128u && (unsigned)gy < 128u)
                patch[p] = orow[gx * 128 + gy];
        }
        __syncthreads();
        for (int i = t; i < K_ / 4; i += 256) {
            const int k0 = i * 4;
            const int gx = k0 >> 7;
            const int dx = gx - wx;
            float4 v = make_float4(0.f, 0.f, 0.f, 0.f);
            float* vp = (float*)&v;
            if (dx >= -R && dx <= R) {
                #pragma unroll
                for (int j = 0; j < 4; ++j) {
                    int gy = (k0 & 127) + j;
                    int dy = gy - wy;
                    if (dy >= -R && dy <= R) {
                        float d2 = (float)(dx * dx + dy * dy);
                        vp[j] = patch[(dx + R) * W + (dy + R)] * (scale * __expf(ninv * d2));
                    }
                }
            }
            *(float4*)&orow[k0] = v;
        }
    } else {
        // general-sigma fallback: full read-modify-write
        for (int i = t; i < K_ / 4; i += 256) {
            float4 v = ((const float4*)orow)[i];
            float* vp = (float*)&v;
            #pragma unroll
            for (int j = 0; j < 4; ++j) {
                int k = i * 4 + j;
                float gx = (float)(k >> 7), gy = (float)(k & 127);
                float dx = gx - (float)wx, dy = gy - (float)wy;
                float d2 = dx * dx + dy * dy;
                vp[j] = vp[j] * (__expf(ninv * d2) * scale);
            }
            ((float4*)orow)[i] = v;
        }
    }
}

// ================= f32 fallback path (unchanged round-3 kernels) =================
__global__ void k2_partial(const float* __restrict__ kmat, float* __restrict__ pk2) {
    int k  = blockIdx.x * 256 + threadIdx.x;
    int d0 = blockIdx.y * 256;
    float s = 0.f;
    #pragma unroll 8
    for (int d = 0; d < 256; ++d) {
        float v = kmat[(size_t)(d0 + d) * K_ + k];
        s = fmaf(v, v, s);
    }
    pk2[(size_t)blockIdx.y * K_ + k] = s;
}

__global__ void k2_reduce(const float* __restrict__ pk2, float* __restrict__ k2) {
    int k = blockIdx.x * 256 + threadIdx.x;
    float s = 0.f;
    #pragma unroll
    for (int j = 0; j < 8; ++j) s += pk2[(size_t)j * K_ + k];
    k2[k] = s;
}

__global__ void x2_kernel(const float* __restrict__ x, float* __restrict__ x2) {
    int row = blockIdx.x;
    const float* xr = x + (size_t)row * D_;
    int t = threadIdx.x;
    float4 v0 = ((const float4*)xr)[t];
    float4 v1 = ((const float4*)xr)[t + 256];
    float s = v0.x*v0.x + v0.y*v0.y + v0.z*v0.z + v0.w*v0.w
            + v1.x*v1.x + v1.y*v1.y + v1.z*v1.z + v1.w*v1.w;
    __shared__ float red[256];
    red[t] = s; __syncthreads();
    for (int off = 128; off > 0; off >>= 1) {
        if (t < off) red[t] += red[t + off];
        __syncthreads();
    }
    if (t == 0) x2[row] = red[0];
}

__global__ __launch_bounds__(256) void gemm_norms(
    const float* __restrict__ X, const float* __restrict__ Kmat,
    const float* __restrict__ x2, const float* __restrict__ k2,
    float* __restrict__ out)
{
    __shared__ float Asf[BD * ASTR];
    __shared__ float Bsf[BD * BN];

    const int tid = threadIdx.x;
    const int tx = tid & 15, ty = tid >> 4;
    const int bn0 = blockIdx.x * BN;
    const int bm0 = blockIdx.y * BM;

    float acc[8][8];
    #pragma unroll
    for (int i = 0; i < 8; ++i)
        #pragma unroll
        for (int j = 0; j < 8; ++j) acc[i][j] = 0.f;

    const int lm = tid >> 2;
    const int ld = (tid & 3) << 2;
    const int bd = tid >> 5;
    const int bk = (tid & 31) << 2;

    const float* Xp = X    + (size_t)(bm0 + lm) * D_ + ld;
    const float* Kp = Kmat + (size_t)bd * K_ + bn0 + bk;

    float4 a0 = *(const float4*)(Xp);
    float4 a1 = *(const float4*)(Xp + (size_t)64 * D_);
    float4 b0 = *(const float4*)(Kp);
    float4 b1 = *(const float4*)(Kp + (size_t)8 * K_);

    const int NT = D_ / BD;
    for (int kt = 0; kt < NT; ++kt) {
        __syncthreads();
        Asf[(ld+0)*ASTR + lm]      = a0.x;
        Asf[(ld+1)*ASTR + lm]      = a0.y;
        Asf[(ld+2)*ASTR + lm]      = a0.z;
        Asf[(ld+3)*ASTR + lm]      = a0.w;
        Asf[(ld+0)*ASTR + lm + 64] = a1.x;
        Asf[(ld+1)*ASTR + lm + 64] = a1.y;
        Asf[(ld+2)*ASTR + lm + 64] = a1.z;
        Asf[(ld+3)*ASTR + lm + 64] = a1.w;
        *(float4*)&Bsf[bd*BN + bk]     = b0;
        *(float4*)&Bsf[(bd+8)*BN + bk] = b1;
        __syncthreads();

        if (kt + 1 < NT) {
            const float* Xn = Xp + (kt + 1) * BD;
            const float* Kn = Kp + (size_t)(kt + 1) * BD * K_;
            a0 = *(const float4*)(Xn);
            a1 = *(const float4*)(Xn + (size_t)64 * D_);
            b0 = *(const float4*)(Kn);
            b1 = *(const float4*)(Kn + (size_t)8 * K_);
        }

        #pragma unroll
        for (int dd = 0; dd < BD; ++dd) {
            float4 A0 = *(const float4*)&Asf[dd*ASTR + ty*4];
            float4 A1 = *(const float4*)&Asf[dd*ASTR + ty*4 + 64];
            float4 B0 = *(const float4*)&Bsf[dd*BN + tx*4];
            float4 B1 = *(const float4*)&Bsf[dd*BN + tx*4 + 64];
            float a[8] = {A0.x,A0.y,A0.z,A0.w,A1.x,A1.y,A1.z,A1.w};
            float b[8] = {B0.x,B0.y,B0.z,B0.w,B1.x,B1.y,B1.z,B1.w};
            #pragma unroll
            for (int i = 0; i < 8; ++i)
                #pragma unroll
                for (int j = 0; j < 8; ++j)
                    acc[i][j] = fmaf(a[i], b[j], acc[i][j]);
        }
    }

    int rl[8], cl[8];
    #pragma unroll
    for (int i = 0; i < 4; ++i) {
        rl[i] = ty*4 + i;  rl[i+4] = ty*4 + 64 + i;
        cl[i] = tx*4 + i;  cl[i+4] = tx*4 + 64 + i;
    }
    float xr[8], kc[8];
    #pragma unroll
    for (int i = 0; i < 8; ++i) { xr[i] = x2[bm0 + rl[i]]; kc[i] = k2[bn0 + cl[i]]; }

    #pragma unroll
    for (int i = 0; i < 8; ++i) {
        float vv[8];
        #pragma unroll
        for (int j = 0; j < 8; ++j)
            vv[j] = fmaxf((xr[i] - 2.f * acc[i][j]) + kc[j], 0.f);
        int gr = bm0 + rl[i];
        *(float4*)&out[(size_t)gr * K_ + bn0 + tx*4]      = make_float4(vv[0],vv[1],vv[2],vv[3]);
        *(float4*)&out[(size_t)gr * K_ + bn0 + tx*4 + 64] = make_float4(vv[4],vv[5],vv[6],vv[7]);
    }
}

__global__ __launch_bounds__(256) void rowscan(
    const float* __restrict__ out, const float* __restrict__ X,
    const float* __restrict__ Kmat, int* __restrict__ widx)
{
    const int row = blockIdx.x;
    const int t = threadIdx.x;
    const float* orow = out + (size_t)row * K_;

    float mn = 3.4e38f;
    for (int i = t; i < K_/4; i += 256) {
        float4 v = ((const float4*)orow)[i];
        mn = fminf(mn, fminf(fminf(v.x, v.y), fminf(v.z, v.w)));
    }
    __shared__ float smin[256];
    smin[t] = mn; __syncthreads();
    for (int off = 128; off > 0; off >>= 1) {
        if (t < off) smin[t] = fminf(smin[t], smin[t+off]);
        __syncthreads();
    }
    const float rowmin = smin[0];

    __shared__ int scnt;
    __shared__ int cand[MAXCAND];
    if (t == 0) scnt = 0;
    __syncthreads();
    const float thr = rowmin + EPS_CAND;
    for (int i = t; i < K_/4; i += 256) {
        float4 v = ((const float4*)orow)[i];
        float vv[4] = {v.x, v.y, v.z, v.w};
        #pragma unroll
        for (int j = 0; j < 4; ++j) {
            if (vv[j] <= thr) {
                int p = atomicAdd(&scnt, 1);
                if (p < MAXCAND) cand[p] = i*4 + j;
            }
        }
    }
    __syncthreads();
    const int cnt = min(scnt, MAXCAND);
    if (cnt == 1) {
        if (t == 0) widx[row] = cand[0];
        return;
    }

    const float* xrow = X + (size_t)row * D_;
    __shared__ double sred[256];
    double xs = 0.0;
    for (int d = t; d < D_; d += 256) {
        float xv = xrow[d];
        float sq = xv * xv;
        xs += (double)sq;
    }
    sred[t] = xs; __syncthreads();
    for (int off = 128; off > 0; off >>= 1) {
        if (t < off) sred[t] += sred[t+off];
        __syncthreads();
    }
    const float x2f = (float)sred[0];
    __syncthreads();

    __shared__ float cscore[MAXCAND];
    for (int c = 0; c < cnt; ++c) {
        const int k = cand[c];
        double dt = 0.0, kk = 0.0;
        for (int d = t; d < D_; d += 256) {
            float wv = Kmat[(size_t)d * K_ + k];
            float xv = xrow[d];
            dt += (double)xv * (double)wv;
            float w2 = wv * wv;
            kk += (double)w2;
        }
        sred[t] = dt; __syncthreads();
        for (int off = 128; off > 0; off >>= 1) {
            if (t < off) sred[t] += sred[t+off];
            __syncthreads();
        }
        const float dotf = (float)sred[0];
        __syncthreads();
        sred[t] = kk; __syncthreads();
        for (int off = 128; off > 0; off >>= 1) {
            if (t < off) sred[t] += sred[t+off];
            __syncthreads();
        }
        if (t == 0) {
            const float k2f = (float)sred[0];
            cscore[c] = fmaxf((x2f - 2.0f * dotf) + k2f, 0.0f);
        }
        __syncthreads();
    }
    if (t == 0) {
        float bv = cscore[0]; int bi = cand[0];
        for (int c = 1; c < cnt; ++c) {
            if (cscore[c] < bv || (cscore[c] == bv && cand[c] < bi)) {
                bv = cscore[c]; bi = cand[c];
            }
        }
        widx[row] = bi;
    }
}

__global__ void finalize(float* __restrict__ out, const int* __restrict__ widx,
                         const float* __restrict__ sigma) {
    size_t gid = (size_t)blockIdx.x * blockDim.x + threadIdx.x;
    int row = (int)(gid / (K_ / 4));
    int c4  = (int)(gid % (K_ / 4)) * 4;
    int w = widx[row];
    float wx = (float)(w >> 7), wy = (float)(w & 127);
    float sg = sigma[0];
    float ninv  = -0.5f / (sg * sg);
    float scale = 1.0f / (sg * sqrtf(2.0f * 3.14159265358979323846f));
    float4 v = *(float4*)&out[(size_t)row * K_ + c4];
    float* vp = (float*)&v;
    #pragma unroll
    for (int j = 0; j < 4; ++j) {
        int k = c4 + j;
        float gx = (float)(k >> 7), gy = (float)(k & 127);
        float dx = gx - wx, dy = gy - wy;
        float d2 = dx*dx + dy*dy;
        vp[j] = vp[j] * (__expf(ninv * d2) * scale);
    }
    *(float4*)&out[(size_t)row * K_ + c4] = v;
}

extern "C" void kernel_launch(void* const* d_in, const int* in_sizes, int n_in,
                              void* d_out, int out_size, void* d_ws, size_t ws_size,
                              hipStream_t stream) {
    const float* x     = (const float*)d_in[0];
    const float* kmat  = (const float*)d_in[1];
    const float* sigma = (const float*)d_in[2];
    float* out = (float*)d_out;

    const size_t BT_BYTES = (size_t)K_ * D_ * 2;   // 64 MB
    const size_t AH_BYTES = (size_t)B_ * D_ * 2;   // 16 MB
    // floats after Bt|Ah: k2[16384] x2[4096] pk2b[32*16384] pmin[64*4096]
    const size_t WS_NEED  = BT_BYTES + AH_BYTES +
        (size_t)(16384 + 4096 + 32*16384 + 64*4096) * 4;

    if (ws_size >= WS_NEED) {
        short* Bt   = (short*)d_ws;
        short* Ahp  = (short*)((char*)d_ws + BT_BYTES);
        float* k2   = (float*)((char*)d_ws + BT_BYTES + AH_BYTES);
        float* x2   = k2 + 16384;
        float* pk2b = x2 + 4096;
        float* pmin = pk2b + 32*16384;

        pack_a_x2 <<<B_, 256, 0, stream>>>(x, Ahp, x2);
        pack_bt_k2<<<dim3(K_/64, D_/64), 256, 0, stream>>>(kmat, Bt, pk2b);
        k2_reduce32<<<K_/256, 256, 0, stream>>>(pk2b, k2);
        gemm_8ph  <<<1024, 512, 0, stream>>>(Ahp, Bt, x2, k2, out, pmin);
        rowpost   <<<B_, 256, 0, stream>>>(out, x, kmat, pmin, sigma);
    } else {
        float* ws = (float*)d_ws;
        float* k2   = ws;
        float* x2   = ws + 16384;
        int*   widx = (int*)(ws + 20480);
        float* pk2  = ws + 24576;

        k2_partial<<<dim3(K_/256, 8), 256, 0, stream>>>(kmat, pk2);
        k2_reduce <<<K_/256, 256, 0, stream>>>(pk2, k2);
        x2_kernel <<<B_, 256, 0, stream>>>(x, x2);
        gemm_norms<<<dim3(K_/BN, BM), 256, 0, stream>>>(x, kmat, x2, k2, out);
        rowscan   <<<B_, 256, 0, stream>>>(out, x, kmat, widx);
        finalize  <<<(size_t)B_ * (K_/4) / 256, 256, 0, stream>>>(out, widx, sigma);
    }
}